// Round 2
// baseline (1144.091 us; speedup 1.0000x reference)
//
#include <hip/hip_runtime.h>
#include <hip/hip_bf16.h>

#define NB 4
#define NH 4
#define TT 2048
#define DKK 64
#define NF 256

#define QT 16
#define KT 64
#define KST 68   // padded LDS stride in floats (272 B = 17*16 -> b128-aligned)

__device__ __forceinline__ float fma4(float4 a, float4 b, float acc) {
    acc = __builtin_fmaf(a.x, b.x, acc);
    acc = __builtin_fmaf(a.y, b.y, acc);
    acc = __builtin_fmaf(a.z, b.z, acc);
    acc = __builtin_fmaf(a.w, b.w, acc);
    return acc;
}

// ---------------- Kernel 1: QKV projection + bias + per-head L2 norm --------
// grid: B*T/16 = 512 blocks, 256 threads. 16 token rows per block.
// Outputs (B,H,T,64) fp32: qn (norm * 0.125 folded in), kn (norm), v.
__global__ __launch_bounds__(256)
void qkv_kernel(const float* __restrict__ query, const float* __restrict__ key,
                const float* __restrict__ value,
                const float* __restrict__ Wq, const float* __restrict__ bq,
                const float* __restrict__ Wk, const float* __restrict__ bk,
                const float* __restrict__ Wv, const float* __restrict__ bv,
                float* __restrict__ qn, float* __restrict__ kn, float* __restrict__ vv)
{
    __shared__ float inq[16][NF], ink[16][NF], inv[16][NF];
    __shared__ float nrm[16][8];
    const int tid = threadIdx.x;
    const int bt0 = blockIdx.x * 16;
    for (int i = tid; i < 16 * NF / 4; i += 256) {
        int r = i >> 6, c4 = i & 63;
        ((float4*)inq[r])[c4] = ((const float4*)(query + (size_t)(bt0 + r) * NF))[c4];
        ((float4*)ink[r])[c4] = ((const float4*)(key   + (size_t)(bt0 + r) * NF))[c4];
        ((float4*)inv[r])[c4] = ((const float4*)(value + (size_t)(bt0 + r) * NF))[c4];
    }
    __syncthreads();
    const int o = tid;  // output feature 0..255
    float aq[16], ak[16], av[16];
    #pragma unroll
    for (int r = 0; r < 16; ++r) { aq[r] = 0.f; ak[r] = 0.f; av[r] = 0.f; }
    const float4* wq4 = (const float4*)(Wq + (size_t)o * NF);
    const float4* wk4 = (const float4*)(Wk + (size_t)o * NF);
    const float4* wv4 = (const float4*)(Wv + (size_t)o * NF);
    for (int j4 = 0; j4 < NF / 4; ++j4) {
        float4 a = wq4[j4], b = wk4[j4], c = wv4[j4];
        #pragma unroll
        for (int r = 0; r < 16; ++r) {
            aq[r] = fma4(a, ((const float4*)inq[r])[j4], aq[r]);
            ak[r] = fma4(b, ((const float4*)ink[r])[j4], ak[r]);
            av[r] = fma4(c, ((const float4*)inv[r])[j4], av[r]);
        }
    }
    const float bqv = bq[o], bkv = bk[o], bvv = bv[o];
    __syncthreads();
    #pragma unroll
    for (int r = 0; r < 16; ++r) {
        inq[r][o] = aq[r] + bqv;
        ink[r][o] = ak[r] + bkv;
    }
    __syncthreads();
    if (tid < 64) {   // 16 rows x 4 heads
        int r = tid >> 2, h = tid & 3;
        float sq = 0.f, sk = 0.f;
        for (int d = 0; d < DKK; ++d) {
            float a = inq[r][h * DKK + d]; sq = __builtin_fmaf(a, a, sq);
            float b = ink[r][h * DKK + d]; sk = __builtin_fmaf(b, b, sk);
        }
        nrm[r][h]     = rsqrtf(sq) * 0.125f;   // fold 1/sqrt(dk) into q
        nrm[r][4 + h] = rsqrtf(sk);
    }
    __syncthreads();
    const int h = o >> 6, d = o & 63;
    #pragma unroll
    for (int r = 0; r < 16; ++r) {
        int bt = bt0 + r;
        int b_ = bt >> 11, t_ = bt & (TT - 1);
        size_t idx = (((size_t)b_ * NH + h) * TT + t_) * DKK + d;
        qn[idx] = (aq[r] + bqv) * nrm[r][h];
        kn[idx] = (ak[r] + bkv) * nrm[r][4 + h];
        vv[idx] = av[r] + bvv;
    }
}

// ---------------- Kernel 2: scores + mask + sparsemax (Michelot) ------------
// grid: B*H*(T/QT) = 2048 blocks, 256 threads.
// Thread (r = tid>>4, l = tid&15): q-row r, 128 score regs.
// score slot m = kt*4+u  <->  column kt*64 + u*16 + l.
__global__ __launch_bounds__(256, 2)
void attn_kernel(const float* __restrict__ qn, const float* __restrict__ kn,
                 const int* __restrict__ mask, float* __restrict__ attn)
{
    __shared__ float qlds[QT][KST];
    __shared__ float klds[KT][KST];
    __shared__ int mlds[TT];
    const int tid = threadIdx.x;
    const int bh = blockIdx.x >> 7;
    const int q0 = (blockIdx.x & 127) * QT;
    const int b_ = bh >> 2;
    const float* qbase = qn + ((size_t)bh * TT + q0) * DKK;
    const float* kbase = kn + (size_t)bh * TT * DKK;
    const int* mrow = mask + b_ * TT;

    {   // stage q tile (16 rows x 64) and mask row
        int r = tid >> 4, c4 = tid & 15;
        float4 v = ((const float4*)(qbase + r * DKK))[c4];
        *(float4*)&qlds[r][c4 * 4] = v;
    }
    for (int i = tid; i < TT / 4; i += 256)
        ((int4*)mlds)[i] = ((const int4*)mrow)[i];
    __syncthreads();

    const int r = tid >> 4;
    const int l = tid & 15;
    float4 q16[16];
    #pragma unroll
    for (int i = 0; i < 16; ++i) q16[i] = *(const float4*)&qlds[r][i * 4];

    float s[128];

    #pragma unroll
    for (int kt = 0; kt < TT / KT; ++kt) {
        __syncthreads();
        const float* kg = kbase + (size_t)kt * KT * DKK;
        #pragma unroll
        for (int i = 0; i < 4; ++i) {
            int idx = tid + 256 * i;
            int row = idx >> 4, c4 = idx & 15;
            float4 v = ((const float4*)(kg + row * DKK))[c4];
            *(float4*)&klds[row][c4 * 4] = v;
        }
        __syncthreads();
        #pragma unroll
        for (int u = 0; u < 4; ++u) {
            const float* kr = klds[l + 16 * u];
            float acc = 0.f;
            #pragma unroll
            for (int d4 = 0; d4 < 16; ++d4)
                acc = fma4(q16[d4], *(const float4*)&kr[d4 * 4], acc);
            s[kt * 4 + u] = acc;   // kt unrolled -> compile-time index
        }
    }

    // mask fill
    #pragma unroll
    for (int m = 0; m < 128; ++m) {
        int col = (m >> 2) * 64 + (m & 3) * 16 + l;
        if (mlds[col] == 0) s[m] = -3.0e38f;
    }

    // Michelot fixed point: tau = (sum_{z>tau} z - 1) / |{z>tau}|
    float S = 0.f, C = 0.f;
    #pragma unroll
    for (int m = 0; m < 128; ++m) {
        bool un = s[m] > -1.0e30f;
        S += un ? s[m] : 0.f;
        C += un ? 1.f : 0.f;
    }
    #pragma unroll
    for (int off = 1; off < 16; off <<= 1) {
        S += __shfl_xor(S, off);
        C += __shfl_xor(C, off);
    }
    float tau; bool done; float prevC = C;
    if (C < 0.5f) { done = true; tau = 3.0e38f; }   // fully-masked row
    else          { done = false; tau = (S - 1.0f) / C; }
    for (int it = 0; it < 100; ++it) {
        if (__all(done)) break;
        if (!done) {
            float S2 = 0.f, C2 = 0.f;
            #pragma unroll
            for (int m = 0; m < 128; ++m) {
                bool in = s[m] > tau;
                S2 += in ? s[m] : 0.f;
                C2 += in ? 1.f : 0.f;
            }
            #pragma unroll
            for (int off = 1; off < 16; off <<= 1) {
                S2 += __shfl_xor(S2, off);
                C2 += __shfl_xor(C2, off);
            }
            if (C2 == prevC) done = true;
            else { tau = (S2 - 1.0f) / C2; prevC = C2; }
        }
    }

    // attn = relu(z - tau); masked entries are -3e38 -> 0
    float* arow = attn + ((size_t)bh * TT + q0 + r) * TT;
    #pragma unroll
    for (int m = 0; m < 128; ++m) {
        int col = (m >> 2) * 64 + (m & 3) * 16 + l;
        float a = s[m] - tau;
        arow[col] = a > 0.f ? a : 0.f;
    }
}

// ---------------- Kernel 3: x = attn @ V ------------------------------------
// grid: B*H*(T/64) = 512 blocks, 256 threads. 64 q-rows per block.
// Thread (rq = tid>>4, dg = tid&15): rows rq*4..rq*4+3, dims dg*4..dg*4+3.
__global__ __launch_bounds__(256)
void pv_kernel(const float* __restrict__ attn, const float* __restrict__ vv,
               float* __restrict__ xout)
{
    __shared__ float alds[64][KST];
    __shared__ float vlds[KT][KST];
    const int tid = threadIdx.x;
    const int bh = blockIdx.x >> 5;
    const int q0 = (blockIdx.x & 31) * 64;
    const int b_ = bh >> 2, h_ = bh & 3;
    const float* abase = attn + ((size_t)bh * TT + q0) * TT;
    const float* vbase = vv + (size_t)bh * TT * DKK;
    const int rq = tid >> 4, dg = tid & 15;
    float4 acc0 = {0,0,0,0}, acc1 = {0,0,0,0}, acc2 = {0,0,0,0}, acc3 = {0,0,0,0};

    for (int ct = 0; ct < TT / KT; ++ct) {
        __syncthreads();
        #pragma unroll
        for (int i = 0; i < 4; ++i) {
            int idx = tid + 256 * i;
            int row = idx >> 4, c4 = idx & 15;
            *(float4*)&alds[row][c4 * 4] =
                ((const float4*)(abase + (size_t)row * TT + ct * KT))[c4];
            *(float4*)&vlds[row][c4 * 4] =
                ((const float4*)(vbase + (size_t)(ct * KT + row) * DKK))[c4];
        }
        __syncthreads();
        #pragma unroll 4
        for (int c = 0; c < KT; ++c) {
            float4 vr = *(const float4*)&vlds[c][dg * 4];
            float a0 = alds[rq * 4 + 0][c];
            float a1 = alds[rq * 4 + 1][c];
            float a2 = alds[rq * 4 + 2][c];
            float a3 = alds[rq * 4 + 3][c];
            acc0.x = __builtin_fmaf(a0, vr.x, acc0.x);
            acc0.y = __builtin_fmaf(a0, vr.y, acc0.y);
            acc0.z = __builtin_fmaf(a0, vr.z, acc0.z);
            acc0.w = __builtin_fmaf(a0, vr.w, acc0.w);
            acc1.x = __builtin_fmaf(a1, vr.x, acc1.x);
            acc1.y = __builtin_fmaf(a1, vr.y, acc1.y);
            acc1.z = __builtin_fmaf(a1, vr.z, acc1.z);
            acc1.w = __builtin_fmaf(a1, vr.w, acc1.w);
            acc2.x = __builtin_fmaf(a2, vr.x, acc2.x);
            acc2.y = __builtin_fmaf(a2, vr.y, acc2.y);
            acc2.z = __builtin_fmaf(a2, vr.z, acc2.z);
            acc2.w = __builtin_fmaf(a2, vr.w, acc2.w);
            acc3.x = __builtin_fmaf(a3, vr.x, acc3.x);
            acc3.y = __builtin_fmaf(a3, vr.y, acc3.y);
            acc3.z = __builtin_fmaf(a3, vr.z, acc3.z);
            acc3.w = __builtin_fmaf(a3, vr.w, acc3.w);
        }
    }

    {
        int t0 = q0 + rq * 4;
        float* xp = xout + ((size_t)b_ * TT + t0) * NF + h_ * DKK + dg * 4;
        *(float4*)(xp + 0 * NF) = acc0;
        *(float4*)(xp + 1 * NF) = acc1;
        *(float4*)(xp + 2 * NF) = acc2;
        *(float4*)(xp + 3 * NF) = acc3;
    }
}

extern "C" void kernel_launch(void* const* d_in, const int* in_sizes, int n_in,
                              void* d_out, int out_size, void* d_ws, size_t ws_size,
                              hipStream_t stream) {
    const float* query = (const float*)d_in[0];
    const float* key   = (const float*)d_in[1];
    const float* value = (const float*)d_in[2];
    const int*   mask  = (const int*)d_in[3];
    const float* Wq = (const float*)d_in[4];
    const float* bq = (const float*)d_in[5];
    const float* Wk = (const float*)d_in[6];
    const float* bk = (const float*)d_in[7];
    const float* Wv = (const float*)d_in[8];
    const float* bv = (const float*)d_in[9];

    float* attn = (float*)d_out;                                 // (B,H,T,T)
    float* x    = (float*)d_out + (size_t)NB * NH * TT * TT;     // (B,T,NF)

    float* qn = (float*)d_ws;                       // (B,H,T,64)
    float* kn = qn + (size_t)NB * NH * TT * DKK;
    float* vv = kn + (size_t)NB * NH * TT * DKK;

    qkv_kernel<<<dim3(NB * TT / 16), dim3(256), 0, stream>>>(
        query, key, value, Wq, bq, Wk, bk, Wv, bv, qn, kn, vv);
    attn_kernel<<<dim3(NB * NH * (TT / QT)), dim3(256), 0, stream>>>(
        qn, kn, mask, attn);
    pv_kernel<<<dim3(NB * NH * (TT / 64)), dim3(256), 0, stream>>>(
        attn, vv, x);
}

// Round 3
// 393.225 us; speedup vs baseline: 2.9095x; 2.9095x over previous
//
#include <hip/hip_runtime.h>
#include <hip/hip_bf16.h>

#define NB 4
#define NH 4
#define TT 2048
#define DKK 64
#define NF 256
#define QT 16
#define KST 68

typedef __attribute__((ext_vector_type(8))) short bf16x8;
typedef __attribute__((ext_vector_type(4))) float f32x4;
typedef __hip_bfloat16 bf16;

__device__ __forceinline__ float fma4(float4 a, float4 b, float acc) {
    acc = __builtin_fmaf(a.x, b.x, acc);
    acc = __builtin_fmaf(a.y, b.y, acc);
    acc = __builtin_fmaf(a.z, b.z, acc);
    acc = __builtin_fmaf(a.w, b.w, acc);
    return acc;
}

// ---------------- Kernel 1: QKV projection + bias + per-head L2 norm --------
// Outputs (B,H,T,64): qn bf16 (norm * 0.125 folded), kn bf16 (norm), vv fp32.
__global__ __launch_bounds__(256)
void qkv_kernel(const float* __restrict__ query, const float* __restrict__ key,
                const float* __restrict__ value,
                const float* __restrict__ Wq, const float* __restrict__ bq,
                const float* __restrict__ Wk, const float* __restrict__ bk,
                const float* __restrict__ Wv, const float* __restrict__ bv,
                bf16* __restrict__ qn, bf16* __restrict__ kn, float* __restrict__ vv)
{
    __shared__ float inq[16][NF], ink[16][NF], inv[16][NF];
    __shared__ float nrm[16][8];
    const int tid = threadIdx.x;
    const int bt0 = blockIdx.x * 16;
    for (int i = tid; i < 16 * NF / 4; i += 256) {
        int r = i >> 6, c4 = i & 63;
        ((float4*)inq[r])[c4] = ((const float4*)(query + (size_t)(bt0 + r) * NF))[c4];
        ((float4*)ink[r])[c4] = ((const float4*)(key   + (size_t)(bt0 + r) * NF))[c4];
        ((float4*)inv[r])[c4] = ((const float4*)(value + (size_t)(bt0 + r) * NF))[c4];
    }
    __syncthreads();
    const int o = tid;  // output feature 0..255
    float aq[16], ak[16], av[16];
    #pragma unroll
    for (int r = 0; r < 16; ++r) { aq[r] = 0.f; ak[r] = 0.f; av[r] = 0.f; }
    const float4* wq4 = (const float4*)(Wq + (size_t)o * NF);
    const float4* wk4 = (const float4*)(Wk + (size_t)o * NF);
    const float4* wv4 = (const float4*)(Wv + (size_t)o * NF);
    for (int j4 = 0; j4 < NF / 4; ++j4) {
        float4 a = wq4[j4], b = wk4[j4], c = wv4[j4];
        #pragma unroll
        for (int r = 0; r < 16; ++r) {
            aq[r] = fma4(a, ((const float4*)inq[r])[j4], aq[r]);
            ak[r] = fma4(b, ((const float4*)ink[r])[j4], ak[r]);
            av[r] = fma4(c, ((const float4*)inv[r])[j4], av[r]);
        }
    }
    const float bqv = bq[o], bkv = bk[o], bvv = bv[o];
    __syncthreads();
    #pragma unroll
    for (int r = 0; r < 16; ++r) {
        inq[r][o] = aq[r] + bqv;
        ink[r][o] = ak[r] + bkv;
    }
    __syncthreads();
    if (tid < 64) {   // 16 rows x 4 heads
        int r = tid >> 2, h = tid & 3;
        float sq = 0.f, sk = 0.f;
        for (int d = 0; d < DKK; ++d) {
            float a = inq[r][h * DKK + d]; sq = __builtin_fmaf(a, a, sq);
            float b = ink[r][h * DKK + d]; sk = __builtin_fmaf(b, b, sk);
        }
        nrm[r][h]     = rsqrtf(sq) * 0.125f;   // fold 1/sqrt(dk) into q
        nrm[r][4 + h] = rsqrtf(sk);
    }
    __syncthreads();
    const int h = o >> 6, d = o & 63;
    #pragma unroll
    for (int r = 0; r < 16; ++r) {
        int bt = bt0 + r;
        int b_ = bt >> 11, t_ = bt & (TT - 1);
        size_t idx = (((size_t)b_ * NH + h) * TT + t_) * DKK + d;
        qn[idx] = __float2bfloat16((aq[r] + bqv) * nrm[r][h]);
        kn[idx] = __float2bfloat16((ak[r] + bkv) * nrm[r][4 + h]);
        vv[idx] = av[r] + bvv;
    }
}

// ---------------- Kernel 2: MFMA scores + mask + sparsemax (Michelot) -------
// grid: B*H*(T/QT) = 2048 blocks, 256 threads = 4 waves.
// Wave w owns k-cols [w*512, w*512+512). S^T mfma: D = mfma(A=k16, B=q16):
// lane holds q-row (lane&15), cols t*16 + (lane>>4)*4 + {0..3} per tile t.
__global__ __launch_bounds__(256, 2)
void attn_kernel(const bf16* __restrict__ qn, const bf16* __restrict__ kn,
                 const int* __restrict__ mask, float* __restrict__ attn)
{
    __shared__ float2 red[4][16];
    const int tid = threadIdx.x;
    const int lane = tid & 63;
    const int w = tid >> 6;
    const int l15 = lane & 15;
    const int g = lane >> 4;            // 0..3
    const int bh = blockIdx.x >> 7;
    const int q0 = (blockIdx.x & 127) * QT;
    const int b_ = bh >> 2;

    const bf16* qbase = qn + ((size_t)bh * TT + q0) * DKK;
    const bf16* kbase = kn + ((size_t)bh * TT + w * 512) * DKK;
    const int* mrow = mask + b_ * TT + w * 512;

    // q B-frags (K=64 -> 2 frags): lane reads q[l15][m*32 + g*8 .. +7]
    bf16x8 qf0 = *(const bf16x8*)(qbase + l15 * DKK + g * 8);
    bf16x8 qf1 = *(const bf16x8*)(qbase + l15 * DKK + 32 + g * 8);

    f32x4 acc[32];
    #pragma unroll
    for (int t = 0; t < 32; ++t) acc[t] = (f32x4){0.f, 0.f, 0.f, 0.f};

    #pragma unroll
    for (int t = 0; t < 32; ++t) {
        const bf16* kp = kbase + (size_t)(t * 16 + l15) * DKK + g * 8;
        bf16x8 kf0 = *(const bf16x8*)(kp);
        bf16x8 kf1 = *(const bf16x8*)(kp + 32);
        acc[t] = __builtin_amdgcn_mfma_f32_16x16x32_bf16(kf0, qf0, acc[t], 0, 0, 0);
        acc[t] = __builtin_amdgcn_mfma_f32_16x16x32_bf16(kf1, qf1, acc[t], 0, 0, 0);
    }

    // fold mask (masked -> -3e38)
    #pragma unroll
    for (int t = 0; t < 32; ++t) {
        int4 mv = *(const int4*)(mrow + t * 16 + g * 4);
        acc[t][0] = mv.x ? acc[t][0] : -3.0e38f;
        acc[t][1] = mv.y ? acc[t][1] : -3.0e38f;
        acc[t][2] = mv.z ? acc[t][2] : -3.0e38f;
        acc[t][3] = mv.w ? acc[t][3] : -3.0e38f;
    }

    // initial sum/count over unmasked
    float S = 0.f, C = 0.f;
    #pragma unroll
    for (int t = 0; t < 32; ++t)
        #pragma unroll
        for (int p = 0; p < 4; ++p) {
            float v = acc[t][p];
            bool un = v > -1.0e30f;
            S += un ? v : 0.f;
            C += un ? 1.f : 0.f;
        }
    S += __shfl_xor(S, 16); C += __shfl_xor(C, 16);
    S += __shfl_xor(S, 32); C += __shfl_xor(C, 32);
    if (lane < 16) red[w][lane] = make_float2(S, C);
    __syncthreads();
    float St = 0.f, Ct = 0.f;
    #pragma unroll
    for (int ww = 0; ww < 4; ++ww) { float2 rr = red[ww][l15]; St += rr.x; Ct += rr.y; }
    float tau = (Ct > 0.5f) ? (St - 1.f) / Ct : 3.0e38f;
    float prevC = Ct;

    // Michelot fixed point: tau <- (sum_{z>tau} z - 1)/|{z>tau}| until support stable
    for (int it = 0; it < 100; ++it) {
        float S2 = 0.f, C2 = 0.f;
        #pragma unroll
        for (int t = 0; t < 32; ++t)
            #pragma unroll
            for (int p = 0; p < 4; ++p) {
                float v = acc[t][p];
                bool in = v > tau;
                S2 += in ? v : 0.f;
                C2 += in ? 1.f : 0.f;
            }
        S2 += __shfl_xor(S2, 16); C2 += __shfl_xor(C2, 16);
        S2 += __shfl_xor(S2, 32); C2 += __shfl_xor(C2, 32);
        __syncthreads();
        if (lane < 16) red[w][lane] = make_float2(S2, C2);
        __syncthreads();
        float S2t = 0.f, C2t = 0.f;
        #pragma unroll
        for (int ww = 0; ww < 4; ++ww) { float2 rr = red[ww][l15]; S2t += rr.x; C2t += rr.y; }
        bool done = (C2t == prevC);
        if (!done) { tau = (S2t - 1.f) / C2t; prevC = C2t; }
        if (__all(done)) break;   // identical across waves: all rows stable
    }

    // attn = relu(z - tau); masked entries (-3e38) -> 0; float4 stores
    float* arow = attn + ((size_t)bh * TT + (q0 + l15)) * TT + w * 512;
    #pragma unroll
    for (int t = 0; t < 32; ++t) {
        f32x4 o;
        #pragma unroll
        for (int p = 0; p < 4; ++p) {
            float a = acc[t][p] - tau;
            o[p] = a > 0.f ? a : 0.f;
        }
        *(f32x4*)(arow + t * 16 + g * 4) = o;
    }
}

// ---------------- Kernel 3: x = attn @ V (fp32 VALU) ------------------------
__global__ __launch_bounds__(256)
void pv_kernel(const float* __restrict__ attn, const float* __restrict__ vv,
               float* __restrict__ xout)
{
    __shared__ float alds[64][KST];
    __shared__ float vlds[64][KST];
    const int tid = threadIdx.x;
    const int bh = blockIdx.x >> 5;
    const int q0 = (blockIdx.x & 31) * 64;
    const int b_ = bh >> 2, h_ = bh & 3;
    const float* abase = attn + ((size_t)bh * TT + q0) * TT;
    const float* vbase = vv + (size_t)bh * TT * DKK;
    const int rq = tid >> 4, dg = tid & 15;
    float4 acc0 = {0,0,0,0}, acc1 = {0,0,0,0}, acc2 = {0,0,0,0}, acc3 = {0,0,0,0};

    for (int ct = 0; ct < TT / 64; ++ct) {
        __syncthreads();
        #pragma unroll
        for (int i = 0; i < 4; ++i) {
            int idx = tid + 256 * i;
            int row = idx >> 4, c4 = idx & 15;
            *(float4*)&alds[row][c4 * 4] =
                ((const float4*)(abase + (size_t)row * TT + ct * 64))[c4];
            *(float4*)&vlds[row][c4 * 4] =
                ((const float4*)(vbase + (size_t)(ct * 64 + row) * DKK))[c4];
        }
        __syncthreads();
        #pragma unroll 4
        for (int c = 0; c < 64; ++c) {
            float4 vr = *(const float4*)&vlds[c][dg * 4];
            float a0 = alds[rq * 4 + 0][c];
            float a1 = alds[rq * 4 + 1][c];
            float a2 = alds[rq * 4 + 2][c];
            float a3 = alds[rq * 4 + 3][c];
            acc0.x = __builtin_fmaf(a0, vr.x, acc0.x);
            acc0.y = __builtin_fmaf(a0, vr.y, acc0.y);
            acc0.z = __builtin_fmaf(a0, vr.z, acc0.z);
            acc0.w = __builtin_fmaf(a0, vr.w, acc0.w);
            acc1.x = __builtin_fmaf(a1, vr.x, acc1.x);
            acc1.y = __builtin_fmaf(a1, vr.y, acc1.y);
            acc1.z = __builtin_fmaf(a1, vr.z, acc1.z);
            acc1.w = __builtin_fmaf(a1, vr.w, acc1.w);
            acc2.x = __builtin_fmaf(a2, vr.x, acc2.x);
            acc2.y = __builtin_fmaf(a2, vr.y, acc2.y);
            acc2.z = __builtin_fmaf(a2, vr.z, acc2.z);
            acc2.w = __builtin_fmaf(a2, vr.w, acc2.w);
            acc3.x = __builtin_fmaf(a3, vr.x, acc3.x);
            acc3.y = __builtin_fmaf(a3, vr.y, acc3.y);
            acc3.z = __builtin_fmaf(a3, vr.z, acc3.z);
            acc3.w = __builtin_fmaf(a3, vr.w, acc3.w);
        }
    }

    {
        int t0 = q0 + rq * 4;
        float* xp = xout + ((size_t)b_ * TT + t0) * NF + h_ * DKK + dg * 4;
        *(float4*)(xp + 0 * NF) = acc0;
        *(float4*)(xp + 1 * NF) = acc1;
        *(float4*)(xp + 2 * NF) = acc2;
        *(float4*)(xp + 3 * NF) = acc3;
    }
}

extern "C" void kernel_launch(void* const* d_in, const int* in_sizes, int n_in,
                              void* d_out, int out_size, void* d_ws, size_t ws_size,
                              hipStream_t stream) {
    const float* query = (const float*)d_in[0];
    const float* key   = (const float*)d_in[1];
    const float* value = (const float*)d_in[2];
    const int*   mask  = (const int*)d_in[3];
    const float* Wq = (const float*)d_in[4];
    const float* bq = (const float*)d_in[5];
    const float* Wk = (const float*)d_in[6];
    const float* bk = (const float*)d_in[7];
    const float* Wv = (const float*)d_in[8];
    const float* bv = (const float*)d_in[9];

    float* attn = (float*)d_out;                                 // (B,H,T,T)
    float* x    = (float*)d_out + (size_t)NB * NH * TT * TT;     // (B,T,NF)

    const size_t NE = (size_t)NB * NH * TT * DKK;                // 2,097,152
    bf16* qn = (bf16*)d_ws;                  // 4 MB
    bf16* kn = qn + NE;                      // 4 MB
    float* vv = (float*)(kn + NE);           // 8 MB

    qkv_kernel<<<dim3(NB * TT / 16), dim3(256), 0, stream>>>(
        query, key, value, Wq, bq, Wk, bk, Wv, bv, qn, kn, vv);
    attn_kernel<<<dim3(NB * NH * (TT / QT)), dim3(256), 0, stream>>>(
        qn, kn, mask, attn);
    pv_kernel<<<dim3(NB * NH * (TT / 64)), dim3(256), 0, stream>>>(
        attn, vv, x);
}

// Round 4
// 288.381 us; speedup vs baseline: 3.9673x; 1.3636x over previous
//
#include <hip/hip_runtime.h>
#include <hip/hip_bf16.h>

#define NB 4
#define NH 4
#define TT 2048
#define DKK 64
#define NF 256
#define QT 16

typedef __attribute__((ext_vector_type(8))) short bf16x8;
typedef __attribute__((ext_vector_type(4))) short s16x4;
typedef __attribute__((ext_vector_type(4))) float f32x4;
typedef __hip_bfloat16 bf16;

__device__ __forceinline__ float fma4(float4 a, float4 b, float acc) {
    acc = __builtin_fmaf(a.x, b.x, acc);
    acc = __builtin_fmaf(a.y, b.y, acc);
    acc = __builtin_fmaf(a.z, b.z, acc);
    acc = __builtin_fmaf(a.w, b.w, acc);
    return acc;
}

__device__ __forceinline__ short f2bs(float f) {
    bf16 h = __float2bfloat16(f);
    return *reinterpret_cast<short*>(&h);
}

// ---------------- Kernel 1: QKV projection + bias + per-head L2 norm --------
// Outputs: qn bf16 (B,H,T,64) (norm*0.125 folded), kn bf16 (B,H,T,64) (norm),
//          vvT bf16 (B,H,64,T) -- transposed V for PV B-fragments.
__global__ __launch_bounds__(256)
void qkv_kernel(const float* __restrict__ query, const float* __restrict__ key,
                const float* __restrict__ value,
                const float* __restrict__ Wq, const float* __restrict__ bq,
                const float* __restrict__ Wk, const float* __restrict__ bk,
                const float* __restrict__ Wv, const float* __restrict__ bv,
                bf16* __restrict__ qn, bf16* __restrict__ kn, bf16* __restrict__ vvT)
{
    __shared__ float inq[16][NF], ink[16][NF], inv[16][NF];
    __shared__ float nrm[16][8];
    const int tid = threadIdx.x;
    const int bt0 = blockIdx.x * 16;
    for (int i = tid; i < 16 * NF / 4; i += 256) {
        int r = i >> 6, c4 = i & 63;
        ((float4*)inq[r])[c4] = ((const float4*)(query + (size_t)(bt0 + r) * NF))[c4];
        ((float4*)ink[r])[c4] = ((const float4*)(key   + (size_t)(bt0 + r) * NF))[c4];
        ((float4*)inv[r])[c4] = ((const float4*)(value + (size_t)(bt0 + r) * NF))[c4];
    }
    __syncthreads();
    const int o = tid;  // output feature 0..255
    float aq[16], ak[16], av[16];
    #pragma unroll
    for (int r = 0; r < 16; ++r) { aq[r] = 0.f; ak[r] = 0.f; av[r] = 0.f; }
    const float4* wq4 = (const float4*)(Wq + (size_t)o * NF);
    const float4* wk4 = (const float4*)(Wk + (size_t)o * NF);
    const float4* wv4 = (const float4*)(Wv + (size_t)o * NF);
    for (int j4 = 0; j4 < NF / 4; ++j4) {
        float4 a = wq4[j4], b = wk4[j4], c = wv4[j4];
        #pragma unroll
        for (int r = 0; r < 16; ++r) {
            aq[r] = fma4(a, ((const float4*)inq[r])[j4], aq[r]);
            ak[r] = fma4(b, ((const float4*)ink[r])[j4], ak[r]);
            av[r] = fma4(c, ((const float4*)inv[r])[j4], av[r]);
        }
    }
    const float bqv = bq[o], bkv = bk[o], bvv = bv[o];
    __syncthreads();
    #pragma unroll
    for (int r = 0; r < 16; ++r) {
        inq[r][o] = aq[r] + bqv;
        ink[r][o] = ak[r] + bkv;
    }
    __syncthreads();
    if (tid < 64) {   // 16 rows x 4 heads
        int r = tid >> 2, h = tid & 3;
        float sq = 0.f, sk = 0.f;
        for (int d = 0; d < DKK; ++d) {
            float a = inq[r][h * DKK + d]; sq = __builtin_fmaf(a, a, sq);
            float b = ink[r][h * DKK + d]; sk = __builtin_fmaf(b, b, sk);
        }
        nrm[r][h]     = rsqrtf(sq) * 0.125f;   // fold 1/sqrt(dk) into q
        nrm[r][4 + h] = rsqrtf(sk);
    }
    __syncthreads();
    const int h = o >> 6, d = o & 63;
    const int b0 = bt0 >> 11, t0 = bt0 & (TT - 1);
    #pragma unroll
    for (int r = 0; r < 16; ++r) {
        size_t idx = (((size_t)b0 * NH + h) * TT + t0 + r) * DKK + d;
        qn[idx] = __float2bfloat16((aq[r] + bqv) * nrm[r][h]);
        kn[idx] = __float2bfloat16((ak[r] + bkv) * nrm[r][4 + h]);
    }
    // V^T bf16: row = (b0*NH+h)*64 + d, 16 consecutive t -> two 16B stores
    bf16x8 v0, v1;
    #pragma unroll
    for (int r = 0; r < 8; ++r) v0[r] = f2bs(av[r] + bvv);
    #pragma unroll
    for (int r = 0; r < 8; ++r) v1[r] = f2bs(av[r + 8] + bvv);
    bf16* vt = vvT + ((size_t)(b0 * NH + h) * DKK + d) * TT + t0;
    *(bf16x8*)(vt)     = v0;
    *(bf16x8*)(vt + 8) = v1;
}

// ------- Kernel 2: MFMA scores + mask + sparsemax (Michelot) + fused PV -----
// grid: B*H*(T/QT) = 2048 blocks, 256 threads = 4 waves.
// Scores: wave w owns k-cols [w*512, w*512+512). D = mfma(A=k16, B=q16):
//   lane(g=lane>>4, l15=lane&15) holds S^T[col=t*16+g*4+p][row=l15].
// PV: P staged bf16 in XOR-swizzled LDS; wave w computes d-slice w*16..+15.
__global__ __launch_bounds__(256, 2)
void attn_kernel(const bf16* __restrict__ qn, const bf16* __restrict__ kn,
                 const bf16* __restrict__ vvT, const int* __restrict__ mask,
                 float* __restrict__ attn, float* __restrict__ xout)
{
    __shared__ short P_s[16 * 2048];          // 64 KB, swizzle: byte ^= (row&7)<<4
    __shared__ float4 red[2][4][16];
    const int tid = threadIdx.x;
    const int lane = tid & 63;
    const int w = tid >> 6;
    const int l15 = lane & 15;
    const int g = lane >> 4;                  // 0..3
    const int bh = blockIdx.x >> 7;
    const int q0 = (blockIdx.x & 127) * QT;
    const int b_ = bh >> 2, h_ = bh & 3;

    const bf16* qbase = qn + ((size_t)bh * TT + q0) * DKK;
    const bf16* kbase = kn + ((size_t)bh * TT + w * 512) * DKK;
    const int* mrow = mask + b_ * TT + w * 512;

    // q B-frags (K=64 -> 2 frags)
    bf16x8 qf0 = *(const bf16x8*)(qbase + l15 * DKK + g * 8);
    bf16x8 qf1 = *(const bf16x8*)(qbase + l15 * DKK + 32 + g * 8);

    f32x4 acc[32];
    #pragma unroll
    for (int t = 0; t < 32; ++t) acc[t] = (f32x4){0.f, 0.f, 0.f, 0.f};

    #pragma unroll
    for (int t = 0; t < 32; ++t) {
        const bf16* kp = kbase + (size_t)(t * 16 + l15) * DKK + g * 8;
        bf16x8 kf0 = *(const bf16x8*)(kp);
        bf16x8 kf1 = *(const bf16x8*)(kp + 32);
        acc[t] = __builtin_amdgcn_mfma_f32_16x16x32_bf16(kf0, qf0, acc[t], 0, 0, 0);
        acc[t] = __builtin_amdgcn_mfma_f32_16x16x32_bf16(kf1, qf1, acc[t], 0, 0, 0);
    }

    // fold mask (masked -> -3e38)
    #pragma unroll
    for (int t = 0; t < 32; ++t) {
        int4 mv = *(const int4*)(mrow + t * 16 + g * 4);
        acc[t][0] = mv.x ? acc[t][0] : -3.0e38f;
        acc[t][1] = mv.y ? acc[t][1] : -3.0e38f;
        acc[t][2] = mv.z ? acc[t][2] : -3.0e38f;
        acc[t][3] = mv.w ? acc[t][3] : -3.0e38f;
    }

    // initial pass: S, C, Q=sum z^2 over unmasked
    float S = 0.f, C = 0.f, Qs = 0.f;
    #pragma unroll
    for (int t = 0; t < 32; ++t)
        #pragma unroll
        for (int p = 0; p < 4; ++p) {
            float v = acc[t][p];
            bool un = v > -1.0e30f;
            float sv = un ? v : 0.f;
            S += sv;
            C += un ? 1.f : 0.f;
            Qs = __builtin_fmaf(sv, sv, Qs);
        }
    S += __shfl_xor(S, 16); C += __shfl_xor(C, 16); Qs += __shfl_xor(Qs, 16);
    S += __shfl_xor(S, 32); C += __shfl_xor(C, 32); Qs += __shfl_xor(Qs, 32);
    int pb = 0;
    if (lane < 16) red[0][w][lane] = make_float4(S, C, Qs, 0.f);
    __syncthreads();
    float St = 0.f, Ct = 0.f, Qt = 0.f;
    #pragma unroll
    for (int ww = 0; ww < 4; ++ww) {
        float4 rr = red[0][ww][l15];
        St += rr.x; Ct += rr.y; Qt += rr.z;
    }
    float tau, prevC;
    if (Ct < 0.5f) {                       // fully-masked row
        tau = 3.0e38f; prevC = 0.f;
    } else {
        float mu = St / Ct;
        float var = Qt / Ct - mu * mu;
        var = var > 0.f ? var : 0.f;
        tau = mu + 1.7f * __builtin_sqrtf(var);   // Newton-safe warm start
        prevC = -1.f;
    }

    // Michelot / Newton: tau <- (sum_{z>tau} z - 1)/|{z>tau}|
    for (int it = 0; it < 64; ++it) {
        float S2 = 0.f, C2 = 0.f;
        #pragma unroll
        for (int t = 0; t < 32; ++t)
            #pragma unroll
            for (int p = 0; p < 4; ++p) {
                float v = acc[t][p];
                bool in = v > tau;
                S2 += in ? v : 0.f;
                C2 += in ? 1.f : 0.f;
            }
        S2 += __shfl_xor(S2, 16); C2 += __shfl_xor(C2, 16);
        S2 += __shfl_xor(S2, 32); C2 += __shfl_xor(C2, 32);
        pb ^= 1;
        if (lane < 16) red[pb][w][lane] = make_float4(S2, C2, 0.f, 0.f);
        __syncthreads();
        float S2t = 0.f, C2t = 0.f;
        #pragma unroll
        for (int ww = 0; ww < 4; ++ww) {
            float4 rr = red[pb][ww][l15];
            S2t += rr.x; C2t += rr.y;
        }
        bool done = (C2t == prevC);
        if (!done) {
            if (C2t < 0.5f) { tau = (St - 1.f) / Ct; prevC = -1.f; } // overshoot: classic restart
            else            { tau = (S2t - 1.f) / C2t; prevC = C2t; }
        }
        if (__all(done)) break;
    }

    // epilogue: attn fp32 to global; P bf16 to swizzled LDS
    float* arow = attn + ((size_t)bh * TT + (q0 + l15)) * TT + w * 512;
    char* prow = (char*)P_s + l15 * 4096;
    const int sw = (l15 & 7) << 4;
    #pragma unroll
    for (int t = 0; t < 32; ++t) {
        f32x4 o;
        s16x4 pb4;
        #pragma unroll
        for (int p = 0; p < 4; ++p) {
            float a = acc[t][p] - tau;
            a = a > 0.f ? a : 0.f;
            o[p] = a;
            pb4[p] = f2bs(a);
        }
        *(f32x4*)(arow + t * 16 + g * 4) = o;
        *(s16x4*)(prow + ((w * 1024 + t * 32 + g * 8) ^ sw)) = pb4;
    }
    __syncthreads();

    // fused PV: wave w computes x[q0..q0+15][h*64 + w*16 .. +15], K = 2048
    f32x4 xacc = (f32x4){0.f, 0.f, 0.f, 0.f};
    const bf16* vt = vvT + ((size_t)bh * DKK + w * 16 + l15) * TT;
    #pragma unroll 8
    for (int kc = 0; kc < 64; ++kc) {
        bf16x8 af = *(const bf16x8*)(prow + ((kc * 64 + g * 16) ^ sw));
        bf16x8 bfr = *(const bf16x8*)(vt + kc * 32 + g * 8);
        xacc = __builtin_amdgcn_mfma_f32_16x16x32_bf16(af, bfr, xacc, 0, 0, 0);
    }
    // D layout: row = g*4+p (q-row), col = l15 (d)
    float* xp = xout + ((size_t)b_ * TT + q0 + g * 4) * NF + h_ * DKK + w * 16 + l15;
    #pragma unroll
    for (int p = 0; p < 4; ++p) xp[p * NF] = xacc[p];
}

extern "C" void kernel_launch(void* const* d_in, const int* in_sizes, int n_in,
                              void* d_out, int out_size, void* d_ws, size_t ws_size,
                              hipStream_t stream) {
    const float* query = (const float*)d_in[0];
    const float* key   = (const float*)d_in[1];
    const float* value = (const float*)d_in[2];
    const int*   mask  = (const int*)d_in[3];
    const float* Wq = (const float*)d_in[4];
    const float* bq = (const float*)d_in[5];
    const float* Wk = (const float*)d_in[6];
    const float* bk = (const float*)d_in[7];
    const float* Wv = (const float*)d_in[8];
    const float* bv = (const float*)d_in[9];

    float* attn = (float*)d_out;                                 // (B,H,T,T)
    float* x    = (float*)d_out + (size_t)NB * NH * TT * TT;     // (B,T,NF)

    const size_t NE = (size_t)NB * NH * TT * DKK;                // 2,097,152
    bf16* qn  = (bf16*)d_ws;                 // 4 MB
    bf16* kn  = qn + NE;                     // 4 MB
    bf16* vvT = kn + NE;                     // 4 MB (B,H,64,T)

    qkv_kernel<<<dim3(NB * TT / 16), dim3(256), 0, stream>>>(
        query, key, value, Wq, bq, Wk, bk, Wv, bv, qn, kn, vvT);
    attn_kernel<<<dim3(NB * NH * (TT / QT)), dim3(256), 0, stream>>>(
        qn, kn, vvT, mask, attn, x);
}

// Round 5
// 236.728 us; speedup vs baseline: 4.8329x; 1.2182x over previous
//
#include <hip/hip_runtime.h>
#include <hip/hip_bf16.h>

#define NB 4
#define NH 4
#define TT 2048
#define DKK 64
#define NF 256
#define QT 16

typedef __attribute__((ext_vector_type(8))) short bf16x8;
typedef __attribute__((ext_vector_type(4))) short s16x4;
typedef __attribute__((ext_vector_type(4))) float f32x4;
typedef __hip_bfloat16 bf16;

__device__ __forceinline__ short f2bs(float f) {
    bf16 h = __float2bfloat16(f);
    return *reinterpret_cast<short*>(&h);
}

// ---------------- Kernel 0: convert W q/k/v fp32 -> bf16 --------------------
// Wb layout: [3][256][256] contiguous (Wq, Wk, Wv row-major).
__global__ __launch_bounds__(256)
void wcvt_kernel(const float* __restrict__ Wq, const float* __restrict__ Wk,
                 const float* __restrict__ Wv, bf16* __restrict__ Wb)
{
    int gid = (blockIdx.x * 256 + threadIdx.x) * 4;   // 192 blocks -> 196608 elems
    const float* src;
    int m = gid >> 16, off = gid & 65535;
    src = (m == 0) ? Wq : (m == 1) ? Wk : Wv;
    float4 v = *(const float4*)(src + off);
    s16x4 o = { f2bs(v.x), f2bs(v.y), f2bs(v.z), f2bs(v.w) };
    *(s16x4*)((short*)Wb + gid) = o;
}

// ---------------- Kernel 1: MFMA QKV projection + bias + L2 norm ------------
// grid: B*T/16 = 512 blocks, 256 threads = 4 waves. Wave w owns head w.
// D = mfma(A=W_rows, B=X_rows): lane(l15,g) holds out[o=w*64+ct*16+g*4+p][xrow=l15].
__global__ __launch_bounds__(256, 4)
void qkv_kernel(const float* __restrict__ query, const float* __restrict__ key,
                const float* __restrict__ value, const bf16* __restrict__ Wb,
                const float* __restrict__ bq, const float* __restrict__ bk,
                const float* __restrict__ bv,
                bf16* __restrict__ qn, bf16* __restrict__ kn, bf16* __restrict__ vvT)
{
    __shared__ char Xq[8192], Xk[8192], Xv[8192];   // [16][256] bf16, XOR-swizzled
    const int tid = threadIdx.x;
    const int bt0 = blockIdx.x * 16;
    const int b0 = bt0 >> 11, t0 = bt0 & (TT - 1);

    {   // stage X bf16 (swizzle: byte ^= (row&7)<<4)
        int row = tid >> 4, c0 = (tid & 15) * 16;
        int swr = (row & 7) << 4;
        const float* qs = query + (size_t)(bt0 + row) * NF + c0;
        const float* ks = key   + (size_t)(bt0 + row) * NF + c0;
        const float* vs = value + (size_t)(bt0 + row) * NF + c0;
        #pragma unroll
        for (int j = 0; j < 4; ++j) {
            float4 a = *(const float4*)(qs + j * 4);
            float4 b = *(const float4*)(ks + j * 4);
            float4 c = *(const float4*)(vs + j * 4);
            int byt = (row * 512 + c0 * 2 + j * 8) ^ swr;
            *(s16x4*)(Xq + byt) = (s16x4){ f2bs(a.x), f2bs(a.y), f2bs(a.z), f2bs(a.w) };
            *(s16x4*)(Xk + byt) = (s16x4){ f2bs(b.x), f2bs(b.y), f2bs(b.z), f2bs(b.w) };
            *(s16x4*)(Xv + byt) = (s16x4){ f2bs(c.x), f2bs(c.y), f2bs(c.z), f2bs(c.w) };
        }
    }
    __syncthreads();

    const int lane = tid & 63;
    const int w = tid >> 6;            // wave = head
    const int l15 = lane & 15;
    const int g = lane >> 4;
    const int swl = (l15 & 7) << 4;

    f32x4 qa[4], ka[4], va[4];
    #pragma unroll
    for (int ct = 0; ct < 4; ++ct) {
        qa[ct] = (f32x4){0.f,0.f,0.f,0.f};
        ka[ct] = (f32x4){0.f,0.f,0.f,0.f};
        va[ct] = (f32x4){0.f,0.f,0.f,0.f};
    }
    const bf16* Wqb = Wb;
    const bf16* Wkb = Wb + 65536;
    const bf16* Wvb = Wb + 131072;

    #pragma unroll
    for (int kt = 0; kt < 8; ++kt) {
        int byt = (l15 * 512 + kt * 64 + g * 16) ^ swl;
        bf16x8 xq = *(const bf16x8*)(Xq + byt);
        bf16x8 xk = *(const bf16x8*)(Xk + byt);
        bf16x8 xv = *(const bf16x8*)(Xv + byt);
        #pragma unroll
        for (int ct = 0; ct < 4; ++ct) {
            size_t wo = (size_t)(w * 64 + ct * 16 + l15) * NF + kt * 32 + g * 8;
            bf16x8 aq = *(const bf16x8*)(Wqb + wo);
            bf16x8 ak = *(const bf16x8*)(Wkb + wo);
            bf16x8 av = *(const bf16x8*)(Wvb + wo);
            qa[ct] = __builtin_amdgcn_mfma_f32_16x16x32_bf16(aq, xq, qa[ct], 0, 0, 0);
            ka[ct] = __builtin_amdgcn_mfma_f32_16x16x32_bf16(ak, xk, ka[ct], 0, 0, 0);
            va[ct] = __builtin_amdgcn_mfma_f32_16x16x32_bf16(av, xv, va[ct], 0, 0, 0);
        }
    }

    // bias (fp32) + norms per (xrow=l15, head=w)
    float qv[4][4], kv[4][4], vv[4][4];
    float sq = 0.f, sk = 0.f;
    #pragma unroll
    for (int ct = 0; ct < 4; ++ct) {
        float4 b4q = *(const float4*)(bq + w * 64 + ct * 16 + g * 4);
        float4 b4k = *(const float4*)(bk + w * 64 + ct * 16 + g * 4);
        float4 b4v = *(const float4*)(bv + w * 64 + ct * 16 + g * 4);
        #pragma unroll
        for (int p = 0; p < 4; ++p) {
            float bqp = (p == 0) ? b4q.x : (p == 1) ? b4q.y : (p == 2) ? b4q.z : b4q.w;
            float bkp = (p == 0) ? b4k.x : (p == 1) ? b4k.y : (p == 2) ? b4k.z : b4k.w;
            float bvp = (p == 0) ? b4v.x : (p == 1) ? b4v.y : (p == 2) ? b4v.z : b4v.w;
            qv[ct][p] = qa[ct][p] + bqp;
            kv[ct][p] = ka[ct][p] + bkp;
            vv[ct][p] = va[ct][p] + bvp;
            sq = __builtin_fmaf(qv[ct][p], qv[ct][p], sq);
            sk = __builtin_fmaf(kv[ct][p], kv[ct][p], sk);
        }
    }
    sq += __shfl_xor(sq, 16); sq += __shfl_xor(sq, 32);
    sk += __shfl_xor(sk, 16); sk += __shfl_xor(sk, 32);
    float nq = rsqrtf(sq) * 0.125f;    // fold 1/sqrt(dk)
    float nk = rsqrtf(sk);

    size_t rowbase = ((size_t)(b0 * NH + w) * TT + t0 + l15) * DKK;
    #pragma unroll
    for (int ct = 0; ct < 4; ++ct) {
        s16x4 oq = { f2bs(qv[ct][0]*nq), f2bs(qv[ct][1]*nq), f2bs(qv[ct][2]*nq), f2bs(qv[ct][3]*nq) };
        s16x4 ok = { f2bs(kv[ct][0]*nk), f2bs(kv[ct][1]*nk), f2bs(kv[ct][2]*nk), f2bs(kv[ct][3]*nk) };
        *(s16x4*)((short*)qn + rowbase + ct * 16 + g * 4) = oq;
        *(s16x4*)((short*)kn + rowbase + ct * 16 + g * 4) = ok;
        #pragma unroll
        for (int p = 0; p < 4; ++p) {
            int d = ct * 16 + g * 4 + p;
            vvT[((size_t)(b0 * NH + w) * DKK + d) * TT + t0 + l15] = __float2bfloat16(vv[ct][p]);
        }
    }
}

// ------- Kernel 2: MFMA scores + mask + sparsemax (Michelot) + fused PV -----
// grid: B*H*(T/QT) = 2048 blocks, 512 threads = 8 waves.
// Wave w owns k-cols [w*256, w*256+256). lane(l15,g): S^T[col=t*16+g*4+p][row=l15].
// PV: wave w -> d-slice (w&3)*16, K-half (w>>2); partials combined via LDS.
__global__ __launch_bounds__(512, 4)
void attn_kernel(const bf16* __restrict__ qn, const bf16* __restrict__ kn,
                 const bf16* __restrict__ vvT, const int* __restrict__ mask,
                 float* __restrict__ attn, float* __restrict__ xout)
{
    __shared__ short P_s[16 * 2048];          // 64 KB, swizzle: byte ^= (row&7)<<4
    __shared__ float4 red[2][8][16];          // 4 KB
    __shared__ float4 xpart[4][64];           // 4 KB
    const int tid = threadIdx.x;
    const int lane = tid & 63;
    const int w = tid >> 6;                   // 0..7
    const int l15 = lane & 15;
    const int g = lane >> 4;                  // 0..3
    const int bh = blockIdx.x >> 7;
    const int q0 = (blockIdx.x & 127) * QT;
    const int b_ = bh >> 2, h_ = bh & 3;

    const bf16* qbase = qn + ((size_t)bh * TT + q0) * DKK;
    const bf16* kbase = kn + ((size_t)bh * TT + w * 256) * DKK;
    const int* mrow = mask + b_ * TT + w * 256;

    bf16x8 qf0 = *(const bf16x8*)(qbase + l15 * DKK + g * 8);
    bf16x8 qf1 = *(const bf16x8*)(qbase + l15 * DKK + 32 + g * 8);

    f32x4 acc[16];
    #pragma unroll
    for (int t = 0; t < 16; ++t) acc[t] = (f32x4){0.f, 0.f, 0.f, 0.f};

    #pragma unroll
    for (int t = 0; t < 16; ++t) {
        const bf16* kp = kbase + (size_t)(t * 16 + l15) * DKK + g * 8;
        bf16x8 kf0 = *(const bf16x8*)(kp);
        bf16x8 kf1 = *(const bf16x8*)(kp + 32);
        acc[t] = __builtin_amdgcn_mfma_f32_16x16x32_bf16(kf0, qf0, acc[t], 0, 0, 0);
        acc[t] = __builtin_amdgcn_mfma_f32_16x16x32_bf16(kf1, qf1, acc[t], 0, 0, 0);
    }

    // fold mask (masked -> -3e38)
    #pragma unroll
    for (int t = 0; t < 16; ++t) {
        int4 mv = *(const int4*)(mrow + t * 16 + g * 4);
        acc[t][0] = mv.x ? acc[t][0] : -3.0e38f;
        acc[t][1] = mv.y ? acc[t][1] : -3.0e38f;
        acc[t][2] = mv.z ? acc[t][2] : -3.0e38f;
        acc[t][3] = mv.w ? acc[t][3] : -3.0e38f;
    }

    // initial pass: S, C, Q=sum z^2 over unmasked
    float S = 0.f, C = 0.f, Qs = 0.f;
    #pragma unroll
    for (int t = 0; t < 16; ++t)
        #pragma unroll
        for (int p = 0; p < 4; ++p) {
            float v = acc[t][p];
            bool un = v > -1.0e30f;
            float sv = un ? v : 0.f;
            S += sv;
            C += un ? 1.f : 0.f;
            Qs = __builtin_fmaf(sv, sv, Qs);
        }
    S += __shfl_xor(S, 16); C += __shfl_xor(C, 16); Qs += __shfl_xor(Qs, 16);
    S += __shfl_xor(S, 32); C += __shfl_xor(C, 32); Qs += __shfl_xor(Qs, 32);
    int pb = 0;
    if (lane < 16) red[0][w][lane] = make_float4(S, C, Qs, 0.f);
    __syncthreads();
    float St = 0.f, Ct = 0.f, Qt = 0.f;
    #pragma unroll
    for (int ww = 0; ww < 8; ++ww) {
        float4 rr = red[0][ww][l15];
        St += rr.x; Ct += rr.y; Qt += rr.z;
    }
    float tau, prevC;
    if (Ct < 0.5f) { tau = 3.0e38f; prevC = 0.f; }
    else {
        float mu = St / Ct;
        float var = Qt / Ct - mu * mu;
        var = var > 0.f ? var : 0.f;
        tau = mu + 1.7f * __builtin_sqrtf(var);   // Newton-safe warm start
        prevC = -1.f;
    }

    // Michelot fixed point
    for (int it = 0; it < 64; ++it) {
        float S2 = 0.f, C2 = 0.f;
        #pragma unroll
        for (int t = 0; t < 16; ++t)
            #pragma unroll
            for (int p = 0; p < 4; ++p) {
                float v = acc[t][p];
                bool in = v > tau;
                S2 += in ? v : 0.f;
                C2 += in ? 1.f : 0.f;
            }
        S2 += __shfl_xor(S2, 16); C2 += __shfl_xor(C2, 16);
        S2 += __shfl_xor(S2, 32); C2 += __shfl_xor(C2, 32);
        pb ^= 1;
        if (lane < 16) red[pb][w][lane] = make_float4(S2, C2, 0.f, 0.f);
        __syncthreads();
        float S2t = 0.f, C2t = 0.f;
        #pragma unroll
        for (int ww = 0; ww < 8; ++ww) {
            float4 rr = red[pb][ww][l15];
            S2t += rr.x; C2t += rr.y;
        }
        bool done = (C2t == prevC);
        if (!done) {
            if (C2t < 0.5f) { tau = (St - 1.f) / Ct; prevC = -1.f; }
            else            { tau = (S2t - 1.f) / C2t; prevC = C2t; }
        }
        if (__all(done)) break;
    }

    // epilogue: attn fp32 to global; P bf16 to swizzled LDS
    float* arow = attn + ((size_t)bh * TT + (q0 + l15)) * TT + w * 256;
    char* prow = (char*)P_s + l15 * 4096;
    const int sw = (l15 & 7) << 4;
    #pragma unroll
    for (int t = 0; t < 16; ++t) {
        f32x4 o;
        s16x4 pb4;
        #pragma unroll
        for (int p = 0; p < 4; ++p) {
            float a = acc[t][p] - tau;
            a = a > 0.f ? a : 0.f;
            o[p] = a;
            pb4[p] = f2bs(a);
        }
        *(f32x4*)(arow + t * 16 + g * 4) = o;
        *(s16x4*)(prow + ((w * 512 + t * 32 + g * 8) ^ sw)) = pb4;
    }
    __syncthreads();

    // fused PV: wave w -> d-slice (w&3)*16, K-half (w>>2)
    const int d0 = (w & 3) * 16;
    const int kh = w >> 2;
    f32x4 xacc = (f32x4){0.f, 0.f, 0.f, 0.f};
    const bf16* vt = vvT + ((size_t)bh * DKK + d0 + l15) * TT + kh * 1024;
    #pragma unroll 8
    for (int kc = 0; kc < 32; ++kc) {
        bf16x8 af = *(const bf16x8*)(prow + ((kh * 2048 + kc * 64 + g * 16) ^ sw));
        bf16x8 bfr = *(const bf16x8*)(vt + kc * 32 + g * 8);
        xacc = __builtin_amdgcn_mfma_f32_16x16x32_bf16(af, bfr, xacc, 0, 0, 0);
    }
    if (w >= 4) xpart[w - 4][lane] = make_float4(xacc[0], xacc[1], xacc[2], xacc[3]);
    __syncthreads();
    if (w < 4) {
        float4 xp4 = xpart[w][lane];
        xacc[0] += xp4.x; xacc[1] += xp4.y; xacc[2] += xp4.z; xacc[3] += xp4.w;
        float* xp = xout + ((size_t)b_ * TT + q0 + g * 4) * NF + h_ * DKK + d0 + l15;
        #pragma unroll
        for (int p = 0; p < 4; ++p) xp[p * NF] = xacc[p];
    }
}

extern "C" void kernel_launch(void* const* d_in, const int* in_sizes, int n_in,
                              void* d_out, int out_size, void* d_ws, size_t ws_size,
                              hipStream_t stream) {
    const float* query = (const float*)d_in[0];
    const float* key   = (const float*)d_in[1];
    const float* value = (const float*)d_in[2];
    const int*   mask  = (const int*)d_in[3];
    const float* Wq = (const float*)d_in[4];
    const float* bq = (const float*)d_in[5];
    const float* Wk = (const float*)d_in[6];
    const float* bk = (const float*)d_in[7];
    const float* Wv = (const float*)d_in[8];
    const float* bv = (const float*)d_in[9];

    float* attn = (float*)d_out;                                 // (B,H,T,T)
    float* x    = (float*)d_out + (size_t)NB * NH * TT * TT;     // (B,T,NF)

    const size_t NE = (size_t)NB * NH * TT * DKK;                // 2,097,152
    bf16* Wb  = (bf16*)d_ws;                 // 3*65536 bf16 = 384 KB
    bf16* qn  = Wb + 3 * 65536;              // 4 MB
    bf16* kn  = qn + NE;                     // 4 MB
    bf16* vvT = kn + NE;                     // 4 MB (B,H,64,T)

    wcvt_kernel<<<dim3(192), dim3(256), 0, stream>>>(Wq, Wk, Wv, Wb);
    qkv_kernel<<<dim3(NB * TT / 16), dim3(256), 0, stream>>>(
        query, key, value, Wb, bq, bk, bv, qn, kn, vvT);
    attn_kernel<<<dim3(NB * NH * (TT / QT)), dim3(512), 0, stream>>>(
        qn, kn, vvT, mask, attn, x);
}

// Round 6
// 164.198 us; speedup vs baseline: 6.9678x; 1.4417x over previous
//
#include <hip/hip_runtime.h>
#include <hip/hip_bf16.h>

#define NB 4
#define NH 4
#define TT 2048
#define DKK 64
#define NF 256
#define QT 16

typedef __attribute__((ext_vector_type(8))) short bf16x8;
typedef __attribute__((ext_vector_type(4))) short s16x4;
typedef __attribute__((ext_vector_type(4))) float f32x4;
typedef __hip_bfloat16 bf16;

__device__ __forceinline__ short f2bs(float f) {
    bf16 h = __float2bfloat16(f);
    return *reinterpret_cast<short*>(&h);
}

// ---------------- Kernel 0: convert W q/k/v fp32 -> bf16 --------------------
__global__ __launch_bounds__(256)
void wcvt_kernel(const float* __restrict__ Wq, const float* __restrict__ Wk,
                 const float* __restrict__ Wv, bf16* __restrict__ Wb)
{
    int gid = (blockIdx.x * 256 + threadIdx.x) * 4;   // 192 blocks -> 196608 elems
    const float* src;
    int m = gid >> 16, off = gid & 65535;
    src = (m == 0) ? Wq : (m == 1) ? Wk : Wv;
    float4 v = *(const float4*)(src + off);
    s16x4 o = { f2bs(v.x), f2bs(v.y), f2bs(v.z), f2bs(v.w) };
    *(s16x4*)((short*)Wb + gid) = o;
}

// ---------------- Kernel 1: MFMA QKV + bias + L2 norm -> fragment layouts ---
// Outputs (all bf16, per bh stride 16384 x 16B):
//  qB[bh][qt][j][lane][8] = q[qt*16+(lane&15)][j*32+(lane>>4)*8+e]
//  kA[bh][kt][j][lane][8] = k[kt*16+(lane&15)][j*32+(lane>>4)*8+e]
//  vB[bh][kc][ds][lane][8] = V[kc*32+(lane>>4)*8+e][ds*16+(lane&15)]
__global__ __launch_bounds__(256, 4)
void qkv_kernel(const float* __restrict__ query, const float* __restrict__ key,
                const float* __restrict__ value, const bf16* __restrict__ Wb,
                const float* __restrict__ bq, const float* __restrict__ bk,
                const float* __restrict__ bv,
                bf16* __restrict__ qB, bf16* __restrict__ kA, bf16* __restrict__ vB)
{
    __shared__ char Xq[8192], Xk[8192], Xv[8192];   // [16][256] bf16, XOR-swizzled
    __shared__ char bounce[24576];                  // qBs 8K | kAs 8K | vBs 8K
    const int tid = threadIdx.x;
    const int bt0 = blockIdx.x * 16;
    const int b0 = bt0 >> 11, t0 = bt0 & (TT - 1);

    {   // stage X bf16 (swizzle: byte ^= (row&7)<<4)
        int row = tid >> 4, c0 = (tid & 15) * 16;
        int swr = (row & 7) << 4;
        const float* qs = query + (size_t)(bt0 + row) * NF + c0;
        const float* ks = key   + (size_t)(bt0 + row) * NF + c0;
        const float* vs = value + (size_t)(bt0 + row) * NF + c0;
        #pragma unroll
        for (int j = 0; j < 4; ++j) {
            float4 a = *(const float4*)(qs + j * 4);
            float4 b = *(const float4*)(ks + j * 4);
            float4 c = *(const float4*)(vs + j * 4);
            int byt = (row * 512 + c0 * 2 + j * 8) ^ swr;
            *(s16x4*)(Xq + byt) = (s16x4){ f2bs(a.x), f2bs(a.y), f2bs(a.z), f2bs(a.w) };
            *(s16x4*)(Xk + byt) = (s16x4){ f2bs(b.x), f2bs(b.y), f2bs(b.z), f2bs(b.w) };
            *(s16x4*)(Xv + byt) = (s16x4){ f2bs(c.x), f2bs(c.y), f2bs(c.z), f2bs(c.w) };
        }
    }
    __syncthreads();

    const int lane = tid & 63;
    const int w = tid >> 6;            // wave = head
    const int l15 = lane & 15;
    const int g = lane >> 4;
    const int swl = (l15 & 7) << 4;

    f32x4 qa[4], ka[4], va[4];
    #pragma unroll
    for (int ct = 0; ct < 4; ++ct) {
        qa[ct] = (f32x4){0.f,0.f,0.f,0.f};
        ka[ct] = (f32x4){0.f,0.f,0.f,0.f};
        va[ct] = (f32x4){0.f,0.f,0.f,0.f};
    }
    const bf16* Wqb = Wb;
    const bf16* Wkb = Wb + 65536;
    const bf16* Wvb = Wb + 131072;

    #pragma unroll
    for (int kt = 0; kt < 8; ++kt) {
        int byt = (l15 * 512 + kt * 64 + g * 16) ^ swl;
        bf16x8 xq = *(const bf16x8*)(Xq + byt);
        bf16x8 xk = *(const bf16x8*)(Xk + byt);
        bf16x8 xv = *(const bf16x8*)(Xv + byt);
        #pragma unroll
        for (int ct = 0; ct < 4; ++ct) {
            size_t wo = (size_t)(w * 64 + ct * 16 + l15) * NF + kt * 32 + g * 8;
            bf16x8 aq = *(const bf16x8*)(Wqb + wo);
            bf16x8 ak = *(const bf16x8*)(Wkb + wo);
            bf16x8 av = *(const bf16x8*)(Wvb + wo);
            qa[ct] = __builtin_amdgcn_mfma_f32_16x16x32_bf16(aq, xq, qa[ct], 0, 0, 0);
            ka[ct] = __builtin_amdgcn_mfma_f32_16x16x32_bf16(ak, xk, ka[ct], 0, 0, 0);
            va[ct] = __builtin_amdgcn_mfma_f32_16x16x32_bf16(av, xv, va[ct], 0, 0, 0);
        }
    }

    // bias (fp32) + norms per (token=l15, head=w); lane holds o=ct*16+g*4+p
    float qv[4][4], kv[4][4], vv[4][4];
    float sq = 0.f, sk = 0.f;
    #pragma unroll
    for (int ct = 0; ct < 4; ++ct) {
        float4 b4q = *(const float4*)(bq + w * 64 + ct * 16 + g * 4);
        float4 b4k = *(const float4*)(bk + w * 64 + ct * 16 + g * 4);
        float4 b4v = *(const float4*)(bv + w * 64 + ct * 16 + g * 4);
        #pragma unroll
        for (int p = 0; p < 4; ++p) {
            float bqp = (p == 0) ? b4q.x : (p == 1) ? b4q.y : (p == 2) ? b4q.z : b4q.w;
            float bkp = (p == 0) ? b4k.x : (p == 1) ? b4k.y : (p == 2) ? b4k.z : b4k.w;
            float bvp = (p == 0) ? b4v.x : (p == 1) ? b4v.y : (p == 2) ? b4v.z : b4v.w;
            qv[ct][p] = qa[ct][p] + bqp;
            kv[ct][p] = ka[ct][p] + bkp;
            vv[ct][p] = va[ct][p] + bvp;
            sq = __builtin_fmaf(qv[ct][p], qv[ct][p], sq);
            sk = __builtin_fmaf(kv[ct][p], kv[ct][p], sk);
        }
    }
    sq += __shfl_xor(sq, 16); sq += __shfl_xor(sq, 32);
    sk += __shfl_xor(sk, 16); sk += __shfl_xor(sk, 32);
    float nq = rsqrtf(sq) * 0.125f;    // fold 1/sqrt(dk)
    float nk = rsqrtf(sk);

    __syncthreads();    // Xq reuse-safe barrier not needed, but orders bounce
    // scatter into bounce (LDS), then contiguous dump
    #pragma unroll
    for (int ct = 0; ct < 4; ++ct) {
        #pragma unroll
        for (int p = 0; p < 4; ++p) {
            int d5 = (ct & 1) * 16 + g * 4 + p;                 // d mod 32
            int qb = w * 2048 + (ct >> 1) * 1024 + (d5 >> 3) * 256 + l15 * 16 + (d5 & 7) * 2;
            *(short*)(bounce + qb)        = f2bs(qv[ct][p] * nq);
            *(short*)(bounce + qb + 8192) = f2bs(kv[ct][p] * nk);
            int vb = 16384 + w * 2048 + ct * 512 + (l15 >> 3) * 256 + (g * 4 + p) * 16 + (l15 & 7) * 2;
            *(short*)(bounce + vb)        = f2bs(vv[ct][p]);
        }
    }
    __syncthreads();

    const int qt = t0 >> 4;                 // also kt
    const int kc = t0 >> 5, h16 = (t0 >> 4) & 1;
    for (int seg = tid; seg < 1536; seg += 256) {
        int byt = seg * 16;
        const char* src = bounce + byt;
        bf16* dst;
        if (byt < 8192) {
            int wh = byt >> 11, off = byt & 2047;
            dst = qB + (((size_t)(b0 * NH + wh)) * 128 + qt) * 1024 + off / 2;
        } else if (byt < 16384) {
            int r = byt - 8192;
            int wh = r >> 11, off = r & 2047;
            dst = kA + (((size_t)(b0 * NH + wh)) * 128 + qt) * 1024 + off / 2;
        } else {
            int r = byt - 16384;
            int wh = r >> 11, ct = (r >> 9) & 3, off = r & 511;
            dst = vB + ((((size_t)(b0 * NH + wh)) * 64 + kc) * 4 + ct) * 512 + h16 * 256 + off / 2;
        }
        *(bf16x8*)dst = *(const bf16x8*)src;
    }
}

// ------- Kernel 2: MFMA scores + sparsemax (Michelot) + attn dump + PV ------
// grid: B*H*(T/QT) = 2048 blocks, 512 threads = 8 waves.
// Wave w owns k-cols [w*256, w*256+256). lane(l15,g): S^T[col=t*16+g*4+p][row=l15].
__global__ __launch_bounds__(512, 4)
void attn_kernel(const bf16* __restrict__ qB, const bf16* __restrict__ kA,
                 const bf16* __restrict__ vB, const int* __restrict__ mask,
                 float* __restrict__ attn, float* __restrict__ xout)
{
    __shared__ short P_s[16 * 2048];          // 64 KB, swizzle: byte ^= (row&7)<<4
    __shared__ float4 red[2][8][16];          // 4 KB
    __shared__ float4 xpart[4][64];           // 4 KB
    const int tid = threadIdx.x;
    const int lane = tid & 63;
    const int w = tid >> 6;                   // 0..7
    const int l15 = lane & 15;
    const int g = lane >> 4;                  // 0..3
    const int bh = blockIdx.x >> 7;
    const int qt = blockIdx.x & 127;
    const int q0 = qt * QT;
    const int b_ = bh >> 2, h_ = bh & 3;

    const size_t fb = (size_t)bh * 16384;     // 16B-unit stride per bh
    const bf16x8* qBv = (const bf16x8*)qB + fb + (size_t)qt * 128;
    const bf16x8* kAv = (const bf16x8*)kA + fb;
    const bf16x8* vBv = (const bf16x8*)vB + fb;
    const int* mrow = mask + b_ * TT + w * 256;

    bf16x8 qf0 = qBv[lane];
    bf16x8 qf1 = qBv[64 + lane];

    f32x4 acc[16];
    #pragma unroll
    for (int t = 0; t < 16; ++t) acc[t] = (f32x4){0.f, 0.f, 0.f, 0.f};

    #pragma unroll
    for (int t = 0; t < 16; ++t) {
        int kt = w * 16 + t;
        bf16x8 kf0 = kAv[(kt * 2 + 0) * 64 + lane];
        bf16x8 kf1 = kAv[(kt * 2 + 1) * 64 + lane];
        acc[t] = __builtin_amdgcn_mfma_f32_16x16x32_bf16(kf0, qf0, acc[t], 0, 0, 0);
        acc[t] = __builtin_amdgcn_mfma_f32_16x16x32_bf16(kf1, qf1, acc[t], 0, 0, 0);
    }

    // fold mask (masked -> -3e38)
    #pragma unroll
    for (int t = 0; t < 16; ++t) {
        int4 mv = *(const int4*)(mrow + t * 16 + g * 4);
        acc[t][0] = mv.x ? acc[t][0] : -3.0e38f;
        acc[t][1] = mv.y ? acc[t][1] : -3.0e38f;
        acc[t][2] = mv.z ? acc[t][2] : -3.0e38f;
        acc[t][3] = mv.w ? acc[t][3] : -3.0e38f;
    }

    // initial pass: S, C, Q=sum z^2 over unmasked
    float S = 0.f, C = 0.f, Qs = 0.f;
    #pragma unroll
    for (int t = 0; t < 16; ++t)
        #pragma unroll
        for (int p = 0; p < 4; ++p) {
            float v = acc[t][p];
            bool un = v > -1.0e30f;
            float sv = un ? v : 0.f;
            S += sv;
            C += un ? 1.f : 0.f;
            Qs = __builtin_fmaf(sv, sv, Qs);
        }
    S += __shfl_xor(S, 16); C += __shfl_xor(C, 16); Qs += __shfl_xor(Qs, 16);
    S += __shfl_xor(S, 32); C += __shfl_xor(C, 32); Qs += __shfl_xor(Qs, 32);
    int pb = 0;
    if (lane < 16) red[0][w][lane] = make_float4(S, C, Qs, 0.f);
    __syncthreads();
    float St = 0.f, Ct = 0.f, Qt = 0.f;
    #pragma unroll
    for (int ww = 0; ww < 8; ++ww) {
        float4 rr = red[0][ww][l15];
        St += rr.x; Ct += rr.y; Qt += rr.z;
    }
    float tau, prevC;
    if (Ct < 0.5f) { tau = 3.0e38f; prevC = 0.f; }
    else {
        float mu = St / Ct;
        float var = Qt / Ct - mu * mu;
        var = var > 0.f ? var : 0.f;
        tau = mu + 1.7f * __builtin_sqrtf(var);   // Newton-safe warm start
        prevC = -1.f;
    }

    // Michelot fixed point
    for (int it = 0; it < 64; ++it) {
        float S2 = 0.f, C2 = 0.f;
        #pragma unroll
        for (int t = 0; t < 16; ++t)
            #pragma unroll
            for (int p = 0; p < 4; ++p) {
                float v = acc[t][p];
                bool in = v > tau;
                S2 += in ? v : 0.f;
                C2 += in ? 1.f : 0.f;
            }
        S2 += __shfl_xor(S2, 16); C2 += __shfl_xor(C2, 16);
        S2 += __shfl_xor(S2, 32); C2 += __shfl_xor(C2, 32);
        pb ^= 1;
        if (lane < 16) red[pb][w][lane] = make_float4(S2, C2, 0.f, 0.f);
        __syncthreads();
        float S2t = 0.f, C2t = 0.f;
        #pragma unroll
        for (int ww = 0; ww < 8; ++ww) {
            float4 rr = red[pb][ww][l15];
            S2t += rr.x; C2t += rr.y;
        }
        bool done = (C2t == prevC);
        if (!done) {
            if (C2t < 0.5f) { tau = (St - 1.f) / Ct; prevC = -1.f; }
            else            { tau = (S2t - 1.f) / C2t; prevC = C2t; }
        }
        if (__all(done)) break;
    }

    // epilogue: P = relu(z - tau) bf16 into swizzled LDS
    char* prow = (char*)P_s + l15 * 4096;
    const int sw = (l15 & 7) << 4;
    #pragma unroll
    for (int t = 0; t < 16; ++t) {
        s16x4 pb4;
        #pragma unroll
        for (int p = 0; p < 4; ++p) {
            float a = acc[t][p] - tau;
            a = a > 0.f ? a : 0.f;
            pb4[p] = f2bs(a);
        }
        *(s16x4*)(prow + ((w * 512 + t * 32 + g * 8) ^ sw)) = pb4;
    }
    __syncthreads();

    // attn dump: wave w streams rows 2w, 2w+1 as contiguous full-line stores
    {
        int row = 2 * w + (lane >> 5);          // 0..15
        int c0 = (lane & 31) * 4;
        const char* pr = (const char*)P_s + row * 4096;
        int swr = (row & 7) << 4;
        float* ar = attn + ((size_t)bh * TT + q0 + row) * TT;
        #pragma unroll
        for (int i = 0; i < 16; ++i) {
            int c = c0 + i * 128;
            uint2 pk = *(const uint2*)(pr + ((c * 2) ^ swr));  // 4 bf16
            f32x4 o;
            o[0] = __uint_as_float(pk.x << 16);
            o[1] = __uint_as_float(pk.x & 0xffff0000u);
            o[2] = __uint_as_float(pk.y << 16);
            o[3] = __uint_as_float(pk.y & 0xffff0000u);
            *(f32x4*)(ar + c) = o;
        }
    }

    // fused PV: wave w -> d-slice ds=(w&3)*16, K-half kh=w>>2
    const int ds = w & 3;
    const int kh = w >> 2;
    f32x4 xacc = (f32x4){0.f, 0.f, 0.f, 0.f};
    #pragma unroll 8
    for (int kcl = 0; kcl < 32; ++kcl) {
        int kc = kh * 32 + kcl;
        bf16x8 af = *(const bf16x8*)(prow + ((kh * 2048 + kcl * 64 + g * 16) ^ sw));
        bf16x8 bfr = vBv[(kc * 4 + ds) * 64 + lane];
        xacc = __builtin_amdgcn_mfma_f32_16x16x32_bf16(af, bfr, xacc, 0, 0, 0);
    }
    if (w >= 4) xpart[w - 4][lane] = make_float4(xacc[0], xacc[1], xacc[2], xacc[3]);
    __syncthreads();
    if (w < 4) {
        float4 xp4 = xpart[w][lane];
        xacc[0] += xp4.x; xacc[1] += xp4.y; xacc[2] += xp4.z; xacc[3] += xp4.w;
        float* xp = xout + ((size_t)b_ * TT + q0 + g * 4) * NF + h_ * DKK + ds * 16 + l15;
        #pragma unroll
        for (int p = 0; p < 4; ++p) xp[p * NF] = xacc[p];
    }
}

extern "C" void kernel_launch(void* const* d_in, const int* in_sizes, int n_in,
                              void* d_out, int out_size, void* d_ws, size_t ws_size,
                              hipStream_t stream) {
    const float* query = (const float*)d_in[0];
    const float* key   = (const float*)d_in[1];
    const float* value = (const float*)d_in[2];
    const int*   mask  = (const int*)d_in[3];
    const float* Wq = (const float*)d_in[4];
    const float* bq = (const float*)d_in[5];
    const float* Wk = (const float*)d_in[6];
    const float* bk = (const float*)d_in[7];
    const float* Wv = (const float*)d_in[8];
    const float* bv = (const float*)d_in[9];

    float* attn = (float*)d_out;                                 // (B,H,T,T)
    float* x    = (float*)d_out + (size_t)NB * NH * TT * TT;     // (B,T,NF)

    const size_t FRAG = (size_t)NB * NH * 16384 * 8;             // 2,097,152 bf16 each
    bf16* Wb = (bf16*)d_ws;                  // 384 KB
    bf16* qB = Wb + 3 * 65536;               // 4 MB
    bf16* kA = qB + FRAG;                    // 4 MB
    bf16* vB = kA + FRAG;                    // 4 MB

    wcvt_kernel<<<dim3(192), dim3(256), 0, stream>>>(Wq, Wk, Wv, Wb);
    qkv_kernel<<<dim3(NB * TT / 16), dim3(256), 0, stream>>>(
        query, key, value, Wb, bq, bk, bv, qB, kA, vB);
    attn_kernel<<<dim3(NB * NH * (TT / QT)), dim3(512), 0, stream>>>(
        qB, kA, vB, mask, attn, x);
}

// Round 7
// 142.653 us; speedup vs baseline: 8.0201x; 1.1510x over previous
//
#include <hip/hip_runtime.h>
#include <hip/hip_bf16.h>

#define NB 4
#define NH 4
#define TT 2048
#define DKK 64
#define NF 256
#define QT 16

typedef __attribute__((ext_vector_type(8))) short bf16x8;
typedef __attribute__((ext_vector_type(4))) short s16x4;
typedef __attribute__((ext_vector_type(4))) float f32x4;
typedef __hip_bfloat16 bf16;

__device__ __forceinline__ short f2bs(float f) {
    bf16 h = __float2bfloat16(f);
    return *reinterpret_cast<short*>(&h);
}
__device__ __forceinline__ float b2f(short s) {
    return __uint_as_float(((unsigned)(unsigned short)s) << 16);
}
__device__ __forceinline__ float wave_sum(float v) {
    #pragma unroll
    for (int off = 1; off < 64; off <<= 1) v += __shfl_xor(v, off);
    return v;
}

// ---------------- Kernel 0: convert W q/k/v fp32 -> bf16 --------------------
__global__ __launch_bounds__(256)
void wcvt_kernel(const float* __restrict__ Wq, const float* __restrict__ Wk,
                 const float* __restrict__ Wv, bf16* __restrict__ Wb)
{
    int gid = (blockIdx.x * 256 + threadIdx.x) * 4;   // 192 blocks -> 196608 elems
    const float* src;
    int m = gid >> 16, off = gid & 65535;
    src = (m == 0) ? Wq : (m == 1) ? Wk : Wv;
    float4 v = *(const float4*)(src + off);
    s16x4 o = { f2bs(v.x), f2bs(v.y), f2bs(v.z), f2bs(v.w) };
    *(s16x4*)((short*)Wb + gid) = o;
}

// ---------------- Kernel 1: MFMA QKV + bias + L2 norm -> fragment layouts ---
// Outputs (all bf16, per bh stride 16384 x 16B):
//  qB[bh][qt][j][lane][8] = q[qt*16+(lane&15)][j*32+(lane>>4)*8+e]
//  kA[bh][kt][j][lane][8] = k[kt*16+(lane&15)][j*32+(lane>>4)*8+e]
//  vB[bh][kc][ds][lane][8] = V[kc*32+(lane>>4)*8+e][ds*16+(lane&15)]
__global__ __launch_bounds__(256, 4)
void qkv_kernel(const float* __restrict__ query, const float* __restrict__ key,
                const float* __restrict__ value, const bf16* __restrict__ Wb,
                const float* __restrict__ bq, const float* __restrict__ bk,
                const float* __restrict__ bv,
                bf16* __restrict__ qB, bf16* __restrict__ kA, bf16* __restrict__ vB)
{
    __shared__ char Xq[8192], Xk[8192], Xv[8192];   // [16][256] bf16, XOR-swizzled
    __shared__ char bounce[24576];                  // qBs 8K | kAs 8K | vBs 8K
    const int tid = threadIdx.x;
    const int bt0 = blockIdx.x * 16;
    const int b0 = bt0 >> 11, t0 = bt0 & (TT - 1);

    {   // stage X bf16 (swizzle: byte ^= (row&7)<<4)
        int row = tid >> 4, c0 = (tid & 15) * 16;
        int swr = (row & 7) << 4;
        const float* qs = query + (size_t)(bt0 + row) * NF + c0;
        const float* ks = key   + (size_t)(bt0 + row) * NF + c0;
        const float* vs = value + (size_t)(bt0 + row) * NF + c0;
        #pragma unroll
        for (int j = 0; j < 4; ++j) {
            float4 a = *(const float4*)(qs + j * 4);
            float4 b = *(const float4*)(ks + j * 4);
            float4 c = *(const float4*)(vs + j * 4);
            int byt = (row * 512 + c0 * 2 + j * 8) ^ swr;
            *(s16x4*)(Xq + byt) = (s16x4){ f2bs(a.x), f2bs(a.y), f2bs(a.z), f2bs(a.w) };
            *(s16x4*)(Xk + byt) = (s16x4){ f2bs(b.x), f2bs(b.y), f2bs(b.z), f2bs(b.w) };
            *(s16x4*)(Xv + byt) = (s16x4){ f2bs(c.x), f2bs(c.y), f2bs(c.z), f2bs(c.w) };
        }
    }
    __syncthreads();

    const int lane = tid & 63;
    const int w = tid >> 6;            // wave = head
    const int l15 = lane & 15;
    const int g = lane >> 4;
    const int swl = (l15 & 7) << 4;

    f32x4 qa[4], ka[4], va[4];
    #pragma unroll
    for (int ct = 0; ct < 4; ++ct) {
        qa[ct] = (f32x4){0.f,0.f,0.f,0.f};
        ka[ct] = (f32x4){0.f,0.f,0.f,0.f};
        va[ct] = (f32x4){0.f,0.f,0.f,0.f};
    }
    const bf16* Wqb = Wb;
    const bf16* Wkb = Wb + 65536;
    const bf16* Wvb = Wb + 131072;

    #pragma unroll
    for (int kt = 0; kt < 8; ++kt) {
        int byt = (l15 * 512 + kt * 64 + g * 16) ^ swl;
        bf16x8 xq = *(const bf16x8*)(Xq + byt);
        bf16x8 xk = *(const bf16x8*)(Xk + byt);
        bf16x8 xv = *(const bf16x8*)(Xv + byt);
        #pragma unroll
        for (int ct = 0; ct < 4; ++ct) {
            size_t wo = (size_t)(w * 64 + ct * 16 + l15) * NF + kt * 32 + g * 8;
            bf16x8 aq = *(const bf16x8*)(Wqb + wo);
            bf16x8 ak = *(const bf16x8*)(Wkb + wo);
            bf16x8 av = *(const bf16x8*)(Wvb + wo);
            qa[ct] = __builtin_amdgcn_mfma_f32_16x16x32_bf16(aq, xq, qa[ct], 0, 0, 0);
            ka[ct] = __builtin_amdgcn_mfma_f32_16x16x32_bf16(ak, xk, ka[ct], 0, 0, 0);
            va[ct] = __builtin_amdgcn_mfma_f32_16x16x32_bf16(av, xv, va[ct], 0, 0, 0);
        }
    }

    // bias (fp32) + norms per (token=l15, head=w); lane holds o=ct*16+g*4+p
    float qv[4][4], kv[4][4], vv[4][4];
    float sq = 0.f, sk = 0.f;
    #pragma unroll
    for (int ct = 0; ct < 4; ++ct) {
        float4 b4q = *(const float4*)(bq + w * 64 + ct * 16 + g * 4);
        float4 b4k = *(const float4*)(bk + w * 64 + ct * 16 + g * 4);
        float4 b4v = *(const float4*)(bv + w * 64 + ct * 16 + g * 4);
        #pragma unroll
        for (int p = 0; p < 4; ++p) {
            float bqp = (p == 0) ? b4q.x : (p == 1) ? b4q.y : (p == 2) ? b4q.z : b4q.w;
            float bkp = (p == 0) ? b4k.x : (p == 1) ? b4k.y : (p == 2) ? b4k.z : b4k.w;
            float bvp = (p == 0) ? b4v.x : (p == 1) ? b4v.y : (p == 2) ? b4v.z : b4v.w;
            qv[ct][p] = qa[ct][p] + bqp;
            kv[ct][p] = ka[ct][p] + bkp;
            vv[ct][p] = va[ct][p] + bvp;
            sq = __builtin_fmaf(qv[ct][p], qv[ct][p], sq);
            sk = __builtin_fmaf(kv[ct][p], kv[ct][p], sk);
        }
    }
    sq += __shfl_xor(sq, 16); sq += __shfl_xor(sq, 32);
    sk += __shfl_xor(sk, 16); sk += __shfl_xor(sk, 32);
    float nq = rsqrtf(sq) * 0.125f;    // fold 1/sqrt(dk)
    float nk = rsqrtf(sk);

    __syncthreads();
    // scatter into bounce (LDS), then contiguous dump
    #pragma unroll
    for (int ct = 0; ct < 4; ++ct) {
        #pragma unroll
        for (int p = 0; p < 4; ++p) {
            int d5 = (ct & 1) * 16 + g * 4 + p;                 // d mod 32
            int qb = w * 2048 + (ct >> 1) * 1024 + (d5 >> 3) * 256 + l15 * 16 + (d5 & 7) * 2;
            *(short*)(bounce + qb)        = f2bs(qv[ct][p] * nq);
            *(short*)(bounce + qb + 8192) = f2bs(kv[ct][p] * nk);
            int vb = 16384 + w * 2048 + ct * 512 + (l15 >> 3) * 256 + (g * 4 + p) * 16 + (l15 & 7) * 2;
            *(short*)(bounce + vb)        = f2bs(vv[ct][p]);
        }
    }
    __syncthreads();

    const int qt = t0 >> 4;                 // also kt
    const int kc = t0 >> 5, h16 = (t0 >> 4) & 1;
    for (int seg = tid; seg < 1536; seg += 256) {
        int byt = seg * 16;
        const char* src = bounce + byt;
        bf16* dst;
        if (byt < 8192) {
            int wh = byt >> 11, off = byt & 2047;
            dst = qB + (((size_t)(b0 * NH + wh)) * 128 + qt) * 1024 + off / 2;
        } else if (byt < 16384) {
            int r = byt - 8192;
            int wh = r >> 11, off = r & 2047;
            dst = kA + (((size_t)(b0 * NH + wh)) * 128 + qt) * 1024 + off / 2;
        } else {
            int r = byt - 16384;
            int wh = r >> 11, ct = (r >> 9) & 3, off = r & 511;
            dst = vB + ((((size_t)(b0 * NH + wh)) * 64 + kc) * 4 + ct) * 512 + h16 * 256 + off / 2;
        }
        *(bf16x8*)dst = *(const bf16x8*)src;
    }
}

// ------- Kernel 2: MFMA scores + wave-local sparsemax + attn + fused PV -----
// grid: B*H*(T/QT) = 2048 blocks, 512 threads = 8 waves.
// Phase 1: wave w computes k-cols [w*256,+256) for all 16 q-rows; masked
//          scores -> bf16 swizzled LDS S_s[16][2048].
// Phase 2: wave w owns q-rows 2w,2w+1 (64 f32/lane); Michelot via shfl only.
// Phase 3: attn = relu(s-tau) fp32 streamed to global; P bf16 back in place.
// Phase 4: PV from P_s + vB fragments.
__global__ __launch_bounds__(512, 4)
void attn_kernel(const bf16* __restrict__ qB, const bf16* __restrict__ kA,
                 const bf16* __restrict__ vB, const int* __restrict__ mask,
                 float* __restrict__ attn, float* __restrict__ xout)
{
    __shared__ short S_s[16 * 2048];          // 64 KB, swizzle: byte ^= (row&7)<<4
    __shared__ float4 xpart[4][64];           // 4 KB
    const int tid = threadIdx.x;
    const int lane = tid & 63;
    const int w = tid >> 6;                   // 0..7
    const int l15 = lane & 15;
    const int g = lane >> 4;                  // 0..3
    const int bh = blockIdx.x >> 7;
    const int qt = blockIdx.x & 127;
    const int q0 = qt * QT;
    const int b_ = bh >> 2, h_ = bh & 3;

    const size_t fb = (size_t)bh * 16384;     // 16B-unit stride per bh
    const bf16x8* qBv = (const bf16x8*)qB + fb + (size_t)qt * 128;
    const bf16x8* kAv = (const bf16x8*)kA + fb;
    const bf16x8* vBv = (const bf16x8*)vB + fb;
    const int* mrow = mask + b_ * TT + w * 256;

    bf16x8 qf0 = qBv[lane];
    bf16x8 qf1 = qBv[64 + lane];

    f32x4 acc[16];
    #pragma unroll
    for (int t = 0; t < 16; ++t) acc[t] = (f32x4){0.f, 0.f, 0.f, 0.f};

    #pragma unroll
    for (int t = 0; t < 16; ++t) {
        int kt = w * 16 + t;
        bf16x8 kf0 = kAv[(kt * 2 + 0) * 64 + lane];
        bf16x8 kf1 = kAv[(kt * 2 + 1) * 64 + lane];
        acc[t] = __builtin_amdgcn_mfma_f32_16x16x32_bf16(kf0, qf0, acc[t], 0, 0, 0);
        acc[t] = __builtin_amdgcn_mfma_f32_16x16x32_bf16(kf1, qf1, acc[t], 0, 0, 0);
    }

    // fold mask, store masked scores bf16 into swizzled LDS
    char* prow = (char*)S_s + l15 * 4096;
    const int sw = (l15 & 7) << 4;
    #pragma unroll
    for (int t = 0; t < 16; ++t) {
        int4 mv = *(const int4*)(mrow + t * 16 + g * 4);
        s16x4 sb;
        sb[0] = mv.x ? f2bs(acc[t][0]) : f2bs(-3.0e38f);
        sb[1] = mv.y ? f2bs(acc[t][1]) : f2bs(-3.0e38f);
        sb[2] = mv.z ? f2bs(acc[t][2]) : f2bs(-3.0e38f);
        sb[3] = mv.w ? f2bs(acc[t][3]) : f2bs(-3.0e38f);
        *(s16x4*)(prow + ((w * 512 + t * 32 + g * 8) ^ sw)) = sb;
    }
    __syncthreads();

    // ---- phase 2: wave-local sparsemax on rows 2w, 2w+1 ----
    // lane holds cols jj*256 + lane*4 .. +3 for jj=0..7  (32 f32 per row)
    const int r0 = 2 * w;
    float va[2][32];
    #pragma unroll
    for (int h = 0; h < 2; ++h) {
        const char* sr = (const char*)S_s + (r0 + h) * 4096;
        int swr = ((r0 + h) & 7) << 4;
        #pragma unroll
        for (int jj = 0; jj < 8; ++jj) {
            s16x4 p4 = *(const s16x4*)(sr + ((jj * 512 + lane * 8) ^ swr));
            va[h][jj * 4 + 0] = b2f(p4[0]);
            va[h][jj * 4 + 1] = b2f(p4[1]);
            va[h][jj * 4 + 2] = b2f(p4[2]);
            va[h][jj * 4 + 3] = b2f(p4[3]);
        }
    }

    float tau[2];
    #pragma unroll
    for (int h = 0; h < 2; ++h) {
        float S = 0.f, C = 0.f, Qs = 0.f;
        #pragma unroll
        for (int i = 0; i < 32; ++i) {
            float v = va[h][i];
            bool un = v > -1.0e30f;
            float sv = un ? v : 0.f;
            S += sv;
            C += un ? 1.f : 0.f;
            Qs = __builtin_fmaf(sv, sv, Qs);
        }
        S = wave_sum(S); C = wave_sum(C); Qs = wave_sum(Qs);
        float tu, prevC;
        bool done;
        if (C < 0.5f) { tu = 3.0e38f; done = true; prevC = 0.f; }
        else {
            float mu = S / C;
            float var = Qs / C - mu * mu;
            var = var > 0.f ? var : 0.f;
            tu = mu + 1.7f * __builtin_sqrtf(var);   // warm start
            prevC = -1.f;
            done = false;
        }
        for (int it = 0; it < 64 && !done; ++it) {
            float S2 = 0.f, C2 = 0.f;
            #pragma unroll
            for (int i = 0; i < 32; ++i) {
                float v = va[h][i];
                bool in = v > tu;
                S2 += in ? v : 0.f;
                C2 += in ? 1.f : 0.f;
            }
            S2 = wave_sum(S2); C2 = wave_sum(C2);
            if (C2 == prevC) done = true;
            else if (C2 < 0.5f) { tu = (S - 1.f) / C; prevC = -1.f; }  // overshoot restart
            else { tu = (S2 - 1.f) / C2; prevC = C2; }
        }
        tau[h] = tu;
    }

    // ---- phase 3: attn fp32 out + P bf16 back into LDS (in place) ----
    #pragma unroll
    for (int h = 0; h < 2; ++h) {
        char* sr = (char*)S_s + (r0 + h) * 4096;
        int swr = ((r0 + h) & 7) << 4;
        float* ar = attn + ((size_t)bh * TT + q0 + r0 + h) * TT;
        float tu = tau[h];
        #pragma unroll
        for (int jj = 0; jj < 8; ++jj) {
            f32x4 o;
            s16x4 pb4;
            #pragma unroll
            for (int e = 0; e < 4; ++e) {
                float a = va[h][jj * 4 + e] - tu;
                a = a > 0.f ? a : 0.f;
                o[e] = a;
                pb4[e] = f2bs(a);
            }
            *(f32x4*)(ar + jj * 256 + lane * 4) = o;
            *(s16x4*)(sr + ((jj * 512 + lane * 8) ^ swr)) = pb4;
        }
    }
    __syncthreads();

    // ---- phase 4: fused PV: wave w -> d-slice ds=(w&3)*16, K-half kh=w>>2 ----
    const int ds = w & 3;
    const int kh = w >> 2;
    f32x4 xacc = (f32x4){0.f, 0.f, 0.f, 0.f};
    #pragma unroll 8
    for (int kcl = 0; kcl < 32; ++kcl) {
        int kc = kh * 32 + kcl;
        bf16x8 af = *(const bf16x8*)(prow + ((kh * 2048 + kcl * 64 + g * 16) ^ sw));
        bf16x8 bfr = vBv[(kc * 4 + ds) * 64 + lane];
        xacc = __builtin_amdgcn_mfma_f32_16x16x32_bf16(af, bfr, xacc, 0, 0, 0);
    }
    if (w >= 4) xpart[w - 4][lane] = make_float4(xacc[0], xacc[1], xacc[2], xacc[3]);
    __syncthreads();
    if (w < 4) {
        float4 xp4 = xpart[w][lane];
        xacc[0] += xp4.x; xacc[1] += xp4.y; xacc[2] += xp4.z; xacc[3] += xp4.w;
        float* xp = xout + ((size_t)b_ * TT + q0 + g * 4) * NF + h_ * DKK + ds * 16 + l15;
        #pragma unroll
        for (int p = 0; p < 4; ++p) xp[p * NF] = xacc[p];
    }
}

extern "C" void kernel_launch(void* const* d_in, const int* in_sizes, int n_in,
                              void* d_out, int out_size, void* d_ws, size_t ws_size,
                              hipStream_t stream) {
    const float* query = (const float*)d_in[0];
    const float* key   = (const float*)d_in[1];
    const float* value = (const float*)d_in[2];
    const int*   mask  = (const int*)d_in[3];
    const float* Wq = (const float*)d_in[4];
    const float* bq = (const float*)d_in[5];
    const float* Wk = (const float*)d_in[6];
    const float* bk = (const float*)d_in[7];
    const float* Wv = (const float*)d_in[8];
    const float* bv = (const float*)d_in[9];

    float* attn = (float*)d_out;                                 // (B,H,T,T)
    float* x    = (float*)d_out + (size_t)NB * NH * TT * TT;     // (B,T,NF)

    const size_t FRAG = (size_t)NB * NH * 16384 * 8;             // 2,097,152 bf16 each
    bf16* Wb = (bf16*)d_ws;                  // 384 KB
    bf16* qB = Wb + 3 * 65536;               // 4 MB
    bf16* kA = qB + FRAG;                    // 4 MB
    bf16* vB = kA + FRAG;                    // 4 MB

    wcvt_kernel<<<dim3(192), dim3(256), 0, stream>>>(Wq, Wk, Wv, Wb);
    qkv_kernel<<<dim3(NB * TT / 16), dim3(256), 0, stream>>>(
        query, key, value, Wb, bq, bk, bv, qB, kA, vB);
    attn_kernel<<<dim3(NB * NH * (TT / QT)), dim3(512), 0, stream>>>(
        qB, kA, vB, mask, attn, x);
}

// Round 8
// 134.893 us; speedup vs baseline: 8.4815x; 1.0575x over previous
//
#include <hip/hip_runtime.h>
#include <hip/hip_bf16.h>

#define NB 4
#define NH 4
#define TT 2048
#define DKK 64
#define NF 256
#define QT 16

typedef __attribute__((ext_vector_type(8))) short bf16x8;
typedef __attribute__((ext_vector_type(4))) short s16x4;
typedef __attribute__((ext_vector_type(4))) float f32x4;
typedef __hip_bfloat16 bf16;

__device__ __forceinline__ short f2bs(float f) {
    bf16 h = __float2bfloat16(f);
    return *reinterpret_cast<short*>(&h);
}
__device__ __forceinline__ float b2f(short s) {
    return __uint_as_float(((unsigned)(unsigned short)s) << 16);
}
__device__ __forceinline__ float wave_sum(float v) {
    #pragma unroll
    for (int off = 1; off < 64; off <<= 1) v += __shfl_xor(v, off);
    return v;
}

// ------- Kernel 0: W fp32 -> bf16, and mask -> bitmask (block 192) ----------
__global__ __launch_bounds__(256)
void wcvt_kernel(const float* __restrict__ Wq, const float* __restrict__ Wk,
                 const float* __restrict__ Wv, const int* __restrict__ mask,
                 bf16* __restrict__ Wb, unsigned* __restrict__ mbits)
{
    if (blockIdx.x == 192) {   // pack mask: 4 batches x 2048 cols -> 256 words
        int t = threadIdx.x;
        const int* mp = mask + t * 32;
        unsigned m = 0;
        #pragma unroll
        for (int j = 0; j < 32; ++j) m |= (mp[j] != 0 ? 1u : 0u) << j;
        mbits[t] = m;
        return;
    }
    int gid = (blockIdx.x * 256 + threadIdx.x) * 4;   // 192 blocks -> 196608 elems
    const float* src;
    int m = gid >> 16, off = gid & 65535;
    src = (m == 0) ? Wq : (m == 1) ? Wk : Wv;
    float4 v = *(const float4*)(src + off);
    s16x4 o = { f2bs(v.x), f2bs(v.y), f2bs(v.z), f2bs(v.w) };
    *(s16x4*)((short*)Wb + gid) = o;
}

// ---------------- Kernel 1: MFMA QKV + bias + L2 norm -> fragment layouts ---
// Outputs (all bf16, per bh stride 16384 x 16B):
//  qB[bh][qt][j][lane][8] = q[qt*16+(lane&15)][j*32+(lane>>4)*8+e]
//  kA[bh][kt][j][lane][8] = k[kt*16+(lane&15)][j*32+(lane>>4)*8+e]
//  vB[bh][kc][ds][lane][8] = V[kc*32+(lane>>4)*8+e][ds*16+(lane&15)]
__global__ __launch_bounds__(256, 4)
void qkv_kernel(const float* __restrict__ query, const float* __restrict__ key,
                const float* __restrict__ value, const bf16* __restrict__ Wb,
                const float* __restrict__ bq, const float* __restrict__ bk,
                const float* __restrict__ bv,
                bf16* __restrict__ qB, bf16* __restrict__ kA, bf16* __restrict__ vB)
{
    __shared__ char Xq[8192], Xk[8192], Xv[8192];   // [16][256] bf16, XOR-swizzled
    __shared__ char bounce[24576];                  // qBs 8K | kAs 8K | vBs 8K
    const int tid = threadIdx.x;
    const int bt0 = blockIdx.x * 16;
    const int b0 = bt0 >> 11, t0 = bt0 & (TT - 1);

    {   // stage X bf16 (swizzle: byte ^= (row&7)<<4)
        int row = tid >> 4, c0 = (tid & 15) * 16;
        int swr = (row & 7) << 4;
        const float* qs = query + (size_t)(bt0 + row) * NF + c0;
        const float* ks = key   + (size_t)(bt0 + row) * NF + c0;
        const float* vs = value + (size_t)(bt0 + row) * NF + c0;
        #pragma unroll
        for (int j = 0; j < 4; ++j) {
            float4 a = *(const float4*)(qs + j * 4);
            float4 b = *(const float4*)(ks + j * 4);
            float4 c = *(const float4*)(vs + j * 4);
            int byt = (row * 512 + c0 * 2 + j * 8) ^ swr;
            *(s16x4*)(Xq + byt) = (s16x4){ f2bs(a.x), f2bs(a.y), f2bs(a.z), f2bs(a.w) };
            *(s16x4*)(Xk + byt) = (s16x4){ f2bs(b.x), f2bs(b.y), f2bs(b.z), f2bs(b.w) };
            *(s16x4*)(Xv + byt) = (s16x4){ f2bs(c.x), f2bs(c.y), f2bs(c.z), f2bs(c.w) };
        }
    }
    __syncthreads();

    const int lane = tid & 63;
    const int w = tid >> 6;            // wave = head
    const int l15 = lane & 15;
    const int g = lane >> 4;
    const int swl = (l15 & 7) << 4;

    f32x4 qa[4], ka[4], va[4];
    #pragma unroll
    for (int ct = 0; ct < 4; ++ct) {
        qa[ct] = (f32x4){0.f,0.f,0.f,0.f};
        ka[ct] = (f32x4){0.f,0.f,0.f,0.f};
        va[ct] = (f32x4){0.f,0.f,0.f,0.f};
    }
    const bf16* Wqb = Wb;
    const bf16* Wkb = Wb + 65536;
    const bf16* Wvb = Wb + 131072;

    #pragma unroll
    for (int kt = 0; kt < 8; ++kt) {
        int byt = (l15 * 512 + kt * 64 + g * 16) ^ swl;
        bf16x8 xq = *(const bf16x8*)(Xq + byt);
        bf16x8 xk = *(const bf16x8*)(Xk + byt);
        bf16x8 xv = *(const bf16x8*)(Xv + byt);
        #pragma unroll
        for (int ct = 0; ct < 4; ++ct) {
            size_t wo = (size_t)(w * 64 + ct * 16 + l15) * NF + kt * 32 + g * 8;
            bf16x8 aq = *(const bf16x8*)(Wqb + wo);
            bf16x8 ak = *(const bf16x8*)(Wkb + wo);
            bf16x8 av = *(const bf16x8*)(Wvb + wo);
            qa[ct] = __builtin_amdgcn_mfma_f32_16x16x32_bf16(aq, xq, qa[ct], 0, 0, 0);
            ka[ct] = __builtin_amdgcn_mfma_f32_16x16x32_bf16(ak, xk, ka[ct], 0, 0, 0);
            va[ct] = __builtin_amdgcn_mfma_f32_16x16x32_bf16(av, xv, va[ct], 0, 0, 0);
        }
    }

    // bias (fp32) + norms per (token=l15, head=w); lane holds o=ct*16+g*4+p
    float qv[4][4], kv[4][4], vv[4][4];
    float sq = 0.f, sk = 0.f;
    #pragma unroll
    for (int ct = 0; ct < 4; ++ct) {
        float4 b4q = *(const float4*)(bq + w * 64 + ct * 16 + g * 4);
        float4 b4k = *(const float4*)(bk + w * 64 + ct * 16 + g * 4);
        float4 b4v = *(const float4*)(bv + w * 64 + ct * 16 + g * 4);
        #pragma unroll
        for (int p = 0; p < 4; ++p) {
            float bqp = (p == 0) ? b4q.x : (p == 1) ? b4q.y : (p == 2) ? b4q.z : b4q.w;
            float bkp = (p == 0) ? b4k.x : (p == 1) ? b4k.y : (p == 2) ? b4k.z : b4k.w;
            float bvp = (p == 0) ? b4v.x : (p == 1) ? b4v.y : (p == 2) ? b4v.z : b4v.w;
            qv[ct][p] = qa[ct][p] + bqp;
            kv[ct][p] = ka[ct][p] + bkp;
            vv[ct][p] = va[ct][p] + bvp;
            sq = __builtin_fmaf(qv[ct][p], qv[ct][p], sq);
            sk = __builtin_fmaf(kv[ct][p], kv[ct][p], sk);
        }
    }
    sq += __shfl_xor(sq, 16); sq += __shfl_xor(sq, 32);
    sk += __shfl_xor(sk, 16); sk += __shfl_xor(sk, 32);
    float nq = rsqrtf(sq) * 0.125f;    // fold 1/sqrt(dk)
    float nk = rsqrtf(sk);

    __syncthreads();
    // scatter into bounce (LDS), then contiguous dump
    #pragma unroll
    for (int ct = 0; ct < 4; ++ct) {
        #pragma unroll
        for (int p = 0; p < 4; ++p) {
            int d5 = (ct & 1) * 16 + g * 4 + p;                 // d mod 32
            int qb = w * 2048 + (ct >> 1) * 1024 + (d5 >> 3) * 256 + l15 * 16 + (d5 & 7) * 2;
            *(short*)(bounce + qb)        = f2bs(qv[ct][p] * nq);
            *(short*)(bounce + qb + 8192) = f2bs(kv[ct][p] * nk);
            int vb = 16384 + w * 2048 + ct * 512 + (l15 >> 3) * 256 + (g * 4 + p) * 16 + (l15 & 7) * 2;
            *(short*)(bounce + vb)        = f2bs(vv[ct][p]);
        }
    }
    __syncthreads();

    const int qt = t0 >> 4;                 // also kt
    const int kc = t0 >> 5, h16 = (t0 >> 4) & 1;
    for (int seg = tid; seg < 1536; seg += 256) {
        int byt = seg * 16;
        const char* src = bounce + byt;
        bf16* dst;
        if (byt < 8192) {
            int wh = byt >> 11, off = byt & 2047;
            dst = qB + (((size_t)(b0 * NH + wh)) * 128 + qt) * 1024 + off / 2;
        } else if (byt < 16384) {
            int r = byt - 8192;
            int wh = r >> 11, off = r & 2047;
            dst = kA + (((size_t)(b0 * NH + wh)) * 128 + qt) * 1024 + off / 2;
        } else {
            int r = byt - 16384;
            int wh = r >> 11, ct = (r >> 9) & 3, off = r & 511;
            dst = vB + ((((size_t)(b0 * NH + wh)) * 64 + kc) * 4 + ct) * 512 + h16 * 256 + off / 2;
        }
        *(bf16x8*)dst = *(const bf16x8*)src;
    }
}

// ------- Kernel 2: MFMA scores + wave-local sparsemax + attn + fused PV -----
// grid: 2048 blocks (XCD-swizzled), 512 threads = 8 waves.
__global__ __launch_bounds__(512, 4)
void attn_kernel(const bf16* __restrict__ qB, const bf16* __restrict__ kA,
                 const bf16* __restrict__ vB, const unsigned* __restrict__ mbits,
                 float* __restrict__ attn, float* __restrict__ xout)
{
    __shared__ short S_s[16 * 2048];          // 64 KB, swizzle: byte ^= (row&7)<<4
    __shared__ float4 xpart[4][64];           // 4 KB
    const int tid = threadIdx.x;
    const int lane = tid & 63;
    const int w = tid >> 6;                   // 0..7
    const int l15 = lane & 15;
    const int g = lane >> 4;                  // 0..3
    // XCD swizzle: 2048 blocks, 8 XCDs -> each XCD owns 2 consecutive bh
    const int swz = (blockIdx.x & 7) * 256 + (blockIdx.x >> 3);
    const int bh = swz >> 7;
    const int qt = swz & 127;
    const int q0 = qt * QT;
    const int b_ = bh >> 2, h_ = bh & 3;

    const size_t fb = (size_t)bh * 16384;     // 16B-unit stride per bh
    const bf16x8* qBv = (const bf16x8*)qB + fb + (size_t)qt * 128;
    const bf16x8* kAv = (const bf16x8*)kA + fb;
    const bf16x8* vBv = (const bf16x8*)vB + fb;

    // mask bits for this wave's 256-col stripe: words w*8..w*8+7
    unsigned mreg[8];
    {
        const unsigned* mwp = mbits + b_ * 64 + w * 8;
        #pragma unroll
        for (int i = 0; i < 8; ++i) mreg[i] = mwp[i];
    }

    bf16x8 qf0 = qBv[lane];
    bf16x8 qf1 = qBv[64 + lane];

    f32x4 acc[16];
    #pragma unroll
    for (int t = 0; t < 16; ++t) acc[t] = (f32x4){0.f, 0.f, 0.f, 0.f};

    #pragma unroll
    for (int t = 0; t < 16; ++t) {
        int kt = w * 16 + t;
        bf16x8 kf0 = kAv[(kt * 2 + 0) * 64 + lane];
        bf16x8 kf1 = kAv[(kt * 2 + 1) * 64 + lane];
        acc[t] = __builtin_amdgcn_mfma_f32_16x16x32_bf16(kf0, qf0, acc[t], 0, 0, 0);
        acc[t] = __builtin_amdgcn_mfma_f32_16x16x32_bf16(kf1, qf1, acc[t], 0, 0, 0);
    }

    // fold mask (bit test), store masked scores bf16 into swizzled LDS
    const short NEGB = (short)0xFF7F;         // bf16 -3.39e38
    char* prow = (char*)S_s + l15 * 4096;
    const int sw = (l15 & 7) << 4;
    #pragma unroll
    for (int t = 0; t < 16; ++t) {
        unsigned bits = mreg[t >> 1] >> (((t & 1) << 4) + (g << 2));
        s16x4 sb;
        sb[0] = (bits & 1) ? f2bs(acc[t][0]) : NEGB;
        sb[1] = (bits & 2) ? f2bs(acc[t][1]) : NEGB;
        sb[2] = (bits & 4) ? f2bs(acc[t][2]) : NEGB;
        sb[3] = (bits & 8) ? f2bs(acc[t][3]) : NEGB;
        *(s16x4*)(prow + ((w * 512 + t * 32 + g * 8) ^ sw)) = sb;
    }
    __syncthreads();

    // ---- phase 2: wave-local sparsemax on rows 2w, 2w+1 ----
    const int r0 = 2 * w;
    float va[2][32];
    #pragma unroll
    for (int h = 0; h < 2; ++h) {
        const char* sr = (const char*)S_s + (r0 + h) * 4096;
        int swr = ((r0 + h) & 7) << 4;
        #pragma unroll
        for (int jj = 0; jj < 8; ++jj) {
            s16x4 p4 = *(const s16x4*)(sr + ((jj * 512 + lane * 8) ^ swr));
            va[h][jj * 4 + 0] = b2f(p4[0]);
            va[h][jj * 4 + 1] = b2f(p4[1]);
            va[h][jj * 4 + 2] = b2f(p4[2]);
            va[h][jj * 4 + 3] = b2f(p4[3]);
        }
    }

    float tau[2];
    #pragma unroll
    for (int h = 0; h < 2; ++h) {
        float S = 0.f, C = 0.f, Qs = 0.f;
        #pragma unroll
        for (int i = 0; i < 32; ++i) {
            float v = va[h][i];
            bool un = v > -1.0e30f;
            float sv = un ? v : 0.f;
            S += sv;
            C += un ? 1.f : 0.f;
            Qs = __builtin_fmaf(sv, sv, Qs);
        }
        S = wave_sum(S); C = wave_sum(C); Qs = wave_sum(Qs);
        float tu, prevC;
        bool done;
        if (C < 0.5f) { tu = 3.0e38f; done = true; prevC = 0.f; }
        else {
            float mu = S / C;
            float var = Qs / C - mu * mu;
            var = var > 0.f ? var : 0.f;
            tu = mu + 1.7f * __builtin_sqrtf(var);   // warm start
            prevC = -1.f;
            done = false;
        }
        for (int it = 0; it < 64 && !done; ++it) {
            float S2 = 0.f, C2 = 0.f;
            #pragma unroll
            for (int i = 0; i < 32; ++i) {
                float v = va[h][i];
                bool in = v > tu;
                S2 += in ? v : 0.f;
                C2 += in ? 1.f : 0.f;
            }
            S2 = wave_sum(S2); C2 = wave_sum(C2);
            if (C2 == prevC) done = true;
            else if (C2 < 0.5f) { tu = (S - 1.f) / C; prevC = -1.f; }  // overshoot restart
            else { tu = (S2 - 1.f) / C2; prevC = C2; }
        }
        tau[h] = tu;
    }

    // ---- phase 3: attn fp32 out (nontemporal) + P bf16 back into LDS ----
    #pragma unroll
    for (int h = 0; h < 2; ++h) {
        char* sr = (char*)S_s + (r0 + h) * 4096;
        int swr = ((r0 + h) & 7) << 4;
        float* ar = attn + ((size_t)bh * TT + q0 + r0 + h) * TT;
        float tu = tau[h];
        #pragma unroll
        for (int jj = 0; jj < 8; ++jj) {
            f32x4 o;
            s16x4 pb4;
            #pragma unroll
            for (int e = 0; e < 4; ++e) {
                float a = va[h][jj * 4 + e] - tu;
                a = a > 0.f ? a : 0.f;
                o[e] = a;
                pb4[e] = f2bs(a);
            }
            __builtin_nontemporal_store(o, (f32x4*)(ar + jj * 256 + lane * 4));
            *(s16x4*)(sr + ((jj * 512 + lane * 8) ^ swr)) = pb4;
        }
    }
    __syncthreads();

    // ---- phase 4: fused PV: wave w -> d-slice ds=(w&3)*16, K-half kh=w>>2 ----
    const int ds = w & 3;
    const int kh = w >> 2;
    f32x4 xacc = (f32x4){0.f, 0.f, 0.f, 0.f};
    #pragma unroll 8
    for (int kcl = 0; kcl < 32; ++kcl) {
        int kc = kh * 32 + kcl;
        bf16x8 af = *(const bf16x8*)(prow + ((kh * 2048 + kcl * 64 + g * 16) ^ sw));
        bf16x8 bfr = vBv[(kc * 4 + ds) * 64 + lane];
        xacc = __builtin_amdgcn_mfma_f32_16x16x32_bf16(af, bfr, xacc, 0, 0, 0);
    }
    if (w >= 4) xpart[w - 4][lane] = make_float4(xacc[0], xacc[1], xacc[2], xacc[3]);
    __syncthreads();
    if (w < 4) {
        float4 xp4 = xpart[w][lane];
        xacc[0] += xp4.x; xacc[1] += xp4.y; xacc[2] += xp4.z; xacc[3] += xp4.w;
        float* xp = xout + ((size_t)b_ * TT + q0 + g * 4) * NF + h_ * DKK + ds * 16 + l15;
        #pragma unroll
        for (int p = 0; p < 4; ++p)
            __builtin_nontemporal_store(xacc[p], xp + p * NF);
    }
}

extern "C" void kernel_launch(void* const* d_in, const int* in_sizes, int n_in,
                              void* d_out, int out_size, void* d_ws, size_t ws_size,
                              hipStream_t stream) {
    const float* query = (const float*)d_in[0];
    const float* key   = (const float*)d_in[1];
    const float* value = (const float*)d_in[2];
    const int*   mask  = (const int*)d_in[3];
    const float* Wq = (const float*)d_in[4];
    const float* bq = (const float*)d_in[5];
    const float* Wk = (const float*)d_in[6];
    const float* bk = (const float*)d_in[7];
    const float* Wv = (const float*)d_in[8];
    const float* bv = (const float*)d_in[9];

    float* attn = (float*)d_out;                                 // (B,H,T,T)
    float* x    = (float*)d_out + (size_t)NB * NH * TT * TT;     // (B,T,NF)

    const size_t FRAG = (size_t)NB * NH * 16384 * 8;             // 2,097,152 bf16 each
    bf16* Wb = (bf16*)d_ws;                  // 384 KB
    bf16* qB = Wb + 3 * 65536;               // 4 MB
    bf16* kA = qB + FRAG;                    // 4 MB
    bf16* vB = kA + FRAG;                    // 4 MB
    unsigned* mbits = (unsigned*)(vB + FRAG);// 1 KB

    wcvt_kernel<<<dim3(193), dim3(256), 0, stream>>>(Wq, Wk, Wv, mask, Wb, mbits);
    qkv_kernel<<<dim3(NB * TT / 16), dim3(256), 0, stream>>>(
        query, key, value, Wb, bq, bk, bv, qB, kA, vB);
    attn_kernel<<<dim3(NB * NH * (TT / QT)), dim3(512), 0, stream>>>(
        qB, kA, vB, mbits, attn, x);
}